// Round 6
// baseline (4243.427 us; speedup 1.0000x reference)
//
#include <hip/hip_runtime.h>
#include <math.h>

typedef unsigned short ushort_t;
typedef short bf16x8 __attribute__((ext_vector_type(8)));   // 8 bf16 = 4 VGPRs (MFMA A/B frag)
typedef float f32x4 __attribute__((ext_vector_type(4)));    // MFMA C/D frag

#define BN_ 4096
#define SN 24
#define TN 24
#define EN 128
#define HN 512
#define GN 1536
#define VN 256
#define BOW_ 1
#define KX 1536   // extended K: [Ahi@Uhi | Alo@Uhi | Ahi@Ulo]
#define HC 1024   // hcat row stride: [hi(512) | lo(512)]

__device__ __forceinline__ float bf2f(ushort_t u) {
    union { unsigned int i; float f; } v; v.i = ((unsigned int)u) << 16; return v.f;
}
__device__ __forceinline__ ushort_t f2bf(float f) {  // round-to-nearest-even
    union { float f; unsigned int i; } v; v.f = f;
    unsigned int r = (v.i + 0x7FFFu + ((v.i >> 16) & 1u)) >> 16;
    return (ushort_t)r;
}

// async global->LDS, 16B per lane. LDS dest = wave-uniform base + lane*16 (HW).
__device__ __forceinline__ void gload16(const void* g, void* l) {
    __builtin_amdgcn_global_load_lds(
        (const __attribute__((address_space(1))) unsigned int*)g,
        (__attribute__((address_space(3))) unsigned int*)l, 16, 0, 0);
}

template<int N> __device__ __forceinline__ void waitcnt_vm() {
    asm volatile("s_waitcnt vmcnt(%0)" :: "n"(N) : "memory");
}
__device__ __forceinline__ void barrier_() { asm volatile("s_barrier" ::: "memory"); }

__global__ void zero_kernel(float4* __restrict__ p, int n16) {
    int i = blockIdx.x * blockDim.x + threadIdx.x;
    if (i < n16) p[i] = make_float4(0.f, 0.f, 0.f, 0.f);
}

// P[mat] = emb @ W + b_input  for (Wf,src), (Wb,src), (Wd,tgt). One block per (mat,row).
__global__ void precomp_P(const float* __restrict__ src_emb, const float* __restrict__ tgt_emb,
                          const float* __restrict__ Wf, const float* __restrict__ bf,
                          const float* __restrict__ Wb, const float* __restrict__ bb,
                          const float* __restrict__ Wd, const float* __restrict__ bd,
                          float* __restrict__ Pf, float* __restrict__ Pb, float* __restrict__ Pd) {
    int mat = blockIdx.x / VN;
    int row = blockIdx.x % VN;
    const float* emb = (mat == 2) ? tgt_emb : src_emb;
    const float* W   = (mat == 0) ? Wf : (mat == 1) ? Wb : Wd;
    const float* bia = (mat == 0) ? bf : (mat == 1) ? bb : bd;
    float* P         = (mat == 0) ? Pf : (mat == 1) ? Pb : Pd;
    __shared__ float e[EN];
    for (int i = threadIdx.x; i < EN; i += blockDim.x) e[i] = emb[row * EN + i];
    __syncthreads();
    for (int c = threadIdx.x; c < GN; c += blockDim.x) {
        float s = bia[c];
#pragma unroll 8
        for (int k = 0; k < EN; k++) s += e[k] * W[k * GN + c];
        P[row * GN + c] = s;
    }
}

// B' tables for the recurrent GEMM: Bt[col][k], k in [0,1536):
//   k<512: bf16hi(U[k][col]); k<1024: bf16hi(U[k-512][col]); k>=1024: bf16lo(U[k-1024][col])
__global__ void precomp_Bt(const float* __restrict__ Uf, const float* __restrict__ Ub,
                           const float* __restrict__ Ud,
                           ushort_t* __restrict__ BtF, ushort_t* __restrict__ BtB,
                           ushort_t* __restrict__ BtD) {
    int mat = blockIdx.x / GN;
    int col = blockIdx.x % GN;
    const float* U = (mat == 0) ? Uf : (mat == 1) ? Ub : Ud;
    ushort_t* Bt   = (mat == 0) ? BtF : (mat == 1) ? BtB : BtD;
    for (int k = threadIdx.x; k < KX; k += blockDim.x) {
        int ke = (k < HN) ? k : (k < 2 * HN) ? (k - HN) : (k - 2 * HN);
        float u = U[ke * GN + col];
        ushort_t hi = f2bf(u);
        Bt[(size_t)col * KX + k] = (k >= 2 * HN) ? f2bf(u - bf2f(hi)) : hi;
    }
}

__global__ void precomp_Wot(const float* __restrict__ Wo, ushort_t* __restrict__ Wot) {
    int col = blockIdx.x;  // 0..255
    for (int k = threadIdx.x; k < KX; k += blockDim.x) {
        int ke = (k < HN) ? k : (k < 2 * HN) ? (k - HN) : (k - 2 * HN);
        float u = Wo[ke * VN + col];
        ushort_t hi = f2bf(u);
        Wot[(size_t)col * KX + k] = (k >= 2 * HN) ? f2bf(u - bf2f(hi)) : hi;
    }
}

// decoder init state = hf_final + hb_final, stored as hi/lo bf16 pair
__global__ void dec_init(const ushort_t* __restrict__ hf, const ushort_t* __restrict__ hb,
                         ushort_t* __restrict__ hd) {
    int i = blockIdx.x * blockDim.x + threadIdx.x;
    if (i >= BN_ * HN) return;
    int row = i >> 9, col = i & (HN - 1);
    float h = bf2f(hf[(size_t)row * HC + col]) + bf2f(hf[(size_t)row * HC + HN + col])
            + bf2f(hb[(size_t)row * HC + col]) + bf2f(hb[(size_t)row * HC + HN + col]);
    ushort_t hi = f2bf(h);
    hd[(size_t)row * HC + col] = hi;
    hd[(size_t)row * HC + HN + col] = f2bf(h - bf2f(hi));
}

// One GRU step via bf16 MFMA split GEMM.
// MT = row tile (128 enc / 64 dec), WR x WC wave grid (WR*WC==4), 256 threads.
// K: 48 chunks of 32. Grid (M-tiles, 8, z): XCD = blockIdx.x%8 -> rows pinned per
// XCD, h-state stays L2-resident across chunks AND steps; Bt streams from L3
// (compulsory 9.2 MB/XCD/step) hidden by PD-deep pipeline.
// Staging: global_load_lds(16B), both-sides XOR swizzle (r4-verified: 0 conflicts).
// PD = 4: quad buffer, 3 chunks in flight, counted vmcnt 3*NST steady state.
template<int MT, int WR, int WC, int PD>
__global__ __launch_bounds__(256) void gru_step(
    const ushort_t* __restrict__ hA_in, ushort_t* __restrict__ hA_out,
    const ushort_t* __restrict__ BtA, const float* __restrict__ brA,
    const float* __restrict__ PA, int modeA,
    const ushort_t* __restrict__ hB_in, ushort_t* __restrict__ hB_out,
    const ushort_t* __restrict__ BtB, const float* __restrict__ brB,
    const float* __restrict__ PB, int modeB,
    const int* __restrict__ tok, int t) {
    const ushort_t* hin; ushort_t* hout; const ushort_t* Bt; const float* brec; const float* P; int mode;
    if (blockIdx.z == 0) { hin = hA_in; hout = hA_out; Bt = BtA; brec = brA; P = PA; mode = modeA; }
    else                 { hin = hB_in; hout = hB_out; Bt = BtB; brec = brB; P = PB; mode = modeB; }

    constexpr int NN = 64 / WC / 16;      // 16-col fragments per wave (2 enc, 1 dec)
    constexpr int NST = MT / 64 + 3;      // gloads issued per wave per stage (5 enc, 4 dec)
    static_assert(PD == 4, "schedule below assumes PD==4");
    const int bm = blockIdx.x * MT;
    const int bj = blockIdx.y * 64;
    const int tid = threadIdx.x;
    const int lane = tid & 63;
    const int w = tid >> 6;
    const int wr = (WR == 1) ? 0 : (w / WC);
    const int wc = (WR == 1) ? w : (w % WC);

    __shared__ __align__(16) short Asm[PD][MT * 32];
    __shared__ __align__(16) short Bsm[PD][192 * 32];

    f32x4 acc[3][4][NN];
#pragma unroll
    for (int g = 0; g < 3; g++)
#pragma unroll
        for (int i = 0; i < 4; i++)
#pragma unroll
            for (int n = 0; n < NN; n++) acc[g][i][n] = (f32x4){0.f, 0.f, 0.f, 0.f};

    const int fl = lane & 15;
    const int fke = (((lane >> 4) ^ ((lane >> 1) & 3)) * 8);    // swizzled read slot
    const int lr = lane >> 2;                                   // staging row in 16-row group
    const int lk = (((lane & 3) ^ ((lane >> 3) & 3)) * 8);      // swizzled global slot

    auto stage = [&](int buf, int kc) {
        const int gk = kc * 32;
        const int agk = (gk >= 2 * HN) ? (gk - 2 * HN) : gk;    // A reuses hi for term 3
#pragma unroll
        for (int s = 0; s < MT / 64; ++s) {
            const int r0 = w * (MT / 4) + s * 16;
            gload16(hin + (size_t)(bm + r0 + lr) * HC + agk + lk, &Asm[buf][r0 * 32]);
        }
#pragma unroll
        for (int s = 0; s < 3; ++s) {
            const int r0 = w * 48 + s * 16;
            const int r = r0 + lr;
            gload16(Bt + (size_t)((r >> 6) * HN + bj + (r & 63)) * KX + gk + lk,
                    &Bsm[buf][r0 * 32]);
        }
    };

    auto compute = [&](int cur) {
        const short* Ab = Asm[cur];
        const short* Bb = Bsm[cur];
        bf16x8 af[4];
#pragma unroll
        for (int i = 0; i < 4; i++)
            af[i] = *(const bf16x8*)&Ab[(wr * 64 + i * 16 + fl) * 32 + fke];
#pragma unroll
        for (int g = 0; g < 3; g++) {
#pragma unroll
            for (int n = 0; n < NN; n++) {
                bf16x8 bfr = *(const bf16x8*)&Bb[(g * 64 + wc * (NN * 16) + n * 16 + fl) * 32 + fke];
#pragma unroll
                for (int i = 0; i < 4; i++)
                    acc[g][i][n] = __builtin_amdgcn_mfma_f32_16x16x32_bf16(af[i], bfr, acc[g][i][n], 0, 0, 0);
            }
        }
    };

    stage(0, 0); stage(1, 1); stage(2, 2);      // prefill PD-1 = 3 chunks

#pragma unroll 4
    for (int kc = 0; kc < 45; ++kc) {           // chunk k lives in buf k&3
        stage((kc + 3) & 3, kc + 3);            // overwrites buf read at kc-1 (tail barrier'd)
        waitcnt_vm<3 * NST>();                  // chunk kc's loads retired; 3 chunks in flight
        barrier_();
        compute(kc & 3);
        barrier_();
    }
    waitcnt_vm<2 * NST>(); barrier_(); compute(1); barrier_();
    waitcnt_vm<NST>();     barrier_(); compute(2); barrier_();
    waitcnt_vm<0>();       barrier_(); compute(3);

    const int fq = lane >> 4;
#pragma unroll
    for (int i = 0; i < 4; i++) {
#pragma unroll
        for (int q = 0; q < 4; q++) {
            const int row = bm + wr * 64 + i * 16 + fq * 4 + q;
            int idx;
            if (mode == 2) idx = (t == 0) ? BOW_ : tok[row * TN + (t - 1)];
            else           idx = tok[row * SN + ((mode == 0) ? t : (SN - 1 - t))];
            const float* Pr = P + (size_t)idx * GN;
#pragma unroll
            for (int n = 0; n < NN; n++) {
                const int col = bj + wc * (NN * 16) + n * 16 + fl;
                float rz = acc[0][i][n][q] + brec[col];
                float rr = acc[1][i][n][q] + brec[HN + col];
                float rh = acc[2][i][n][q] + brec[2 * HN + col];
                float z = 1.f / (1.f + expf(-(Pr[col] + rz)));
                float r = 1.f / (1.f + expf(-(Pr[HN + col] + rr)));
                float hh = tanhf(Pr[2 * HN + col] + r * rh);
                float ho = bf2f(hin[(size_t)row * HC + col]) + bf2f(hin[(size_t)row * HC + HN + col]);
                float hnew = z * ho + (1.f - z) * hh;
                ushort_t hib = f2bf(hnew);
                hout[(size_t)row * HC + col] = hib;
                hout[(size_t)row * HC + HN + col] = f2bf(hnew - bf2f(hib));
            }
        }
    }
}

// logits[:, t, :] = hd @ Wo + bo via split GEMM. M=4096, N=256, K=1536(split).
// 64-row x 64-col tiles, grid (64,4): XCD = bx%8 (row-pinned, Wot 0.75MB L2-resident).
// 4 waves of 64x16; PD=4 quad buffer, NST=2.
__global__ __launch_bounds__(256) void logits_mfma(
    const ushort_t* __restrict__ hin, const ushort_t* __restrict__ Wot,
    const float* __restrict__ bo, float* __restrict__ out, int t) {
    const int bm = blockIdx.x * 64;
    const int bn = blockIdx.y * 64;
    const int tid = threadIdx.x;
    const int lane = tid & 63;
    const int w = tid >> 6;   // wc

    __shared__ __align__(16) short Asm[4][64 * 32];
    __shared__ __align__(16) short Bsm[4][64 * 32];

    f32x4 acc[4];
#pragma unroll
    for (int i = 0; i < 4; i++) acc[i] = (f32x4){0.f, 0.f, 0.f, 0.f};

    const int fl = lane & 15;
    const int fke = (((lane >> 4) ^ ((lane >> 1) & 3)) * 8);
    const int lr = lane >> 2;
    const int lk = (((lane & 3) ^ ((lane >> 3) & 3)) * 8);

    auto stage = [&](int buf, int kc) {
        const int gk = kc * 32;
        const int agk = (gk >= 2 * HN) ? (gk - 2 * HN) : gk;
        const int r0 = w * 16;
        gload16(hin + (size_t)(bm + r0 + lr) * HC + agk + lk, &Asm[buf][r0 * 32]);
        gload16(Wot + (size_t)(bn + r0 + lr) * KX + gk + lk, &Bsm[buf][r0 * 32]);
    };

    auto compute = [&](int cur) {
        const short* Ab = Asm[cur];
        const short* Bb = Bsm[cur];
        bf16x8 bfr = *(const bf16x8*)&Bb[(w * 16 + fl) * 32 + fke];
#pragma unroll
        for (int i = 0; i < 4; i++) {
            bf16x8 af = *(const bf16x8*)&Ab[(i * 16 + fl) * 32 + fke];
            acc[i] = __builtin_amdgcn_mfma_f32_16x16x32_bf16(af, bfr, acc[i], 0, 0, 0);
        }
    };

    stage(0, 0); stage(1, 1); stage(2, 2);

#pragma unroll 4
    for (int kc = 0; kc < 45; ++kc) {
        stage((kc + 3) & 3, kc + 3);
        waitcnt_vm<6>();
        barrier_();
        compute(kc & 3);
        barrier_();
    }
    waitcnt_vm<4>(); barrier_(); compute(1); barrier_();
    waitcnt_vm<2>(); barrier_(); compute(2); barrier_();
    waitcnt_vm<0>(); barrier_(); compute(3);

    const int fq = lane >> 4;
#pragma unroll
    for (int i = 0; i < 4; i++) {
#pragma unroll
        for (int q = 0; q < 4; q++) {
            const int row = bm + i * 16 + fq * 4 + q;
            const int col = bn + w * 16 + fl;
            out[(size_t)row * (TN * VN) + t * VN + col] = acc[i][q] + bo[col];
        }
    }
}

extern "C" void kernel_launch(void* const* d_in, const int* in_sizes, int n_in,
                              void* d_out, int out_size, void* d_ws, size_t ws_size,
                              hipStream_t stream) {
    const int* source    = (const int*)d_in[0];
    const int* targets   = (const int*)d_in[1];
    const float* src_emb = (const float*)d_in[2];
    const float* tgt_emb = (const float*)d_in[3];
    const float* Wf = (const float*)d_in[4];
    const float* Uf = (const float*)d_in[5];
    const float* bf = (const float*)d_in[6];
    const float* Wb = (const float*)d_in[7];
    const float* Ub = (const float*)d_in[8];
    const float* bb = (const float*)d_in[9];
    const float* Wd = (const float*)d_in[10];
    const float* Ud = (const float*)d_in[11];
    const float* bd = (const float*)d_in[12];
    const float* Wo = (const float*)d_in[13];
    const float* bo = (const float*)d_in[14];
    float* out = (float*)d_out;

    char* ws = (char*)d_ws;
    ushort_t* BtF = (ushort_t*)(ws);                              // 1536*1536*2 = 4718592
    ushort_t* BtB = (ushort_t*)(ws + 4718592);
    ushort_t* BtD = (ushort_t*)(ws + 2 * 4718592);
    ushort_t* Wot = (ushort_t*)(ws + 3 * 4718592);                // 256*1536*2 = 786432
    float*    Pf  = (float*)   (ws + 3 * 4718592 + 786432);       // 3*256*1536*4 = 4718592
    float*    Pb  = Pf + VN * GN;
    float*    Pd  = Pb + VN * GN;
    char* hbase = ws + 4 * 4718592 + 786432;                      // 4 x 4096*1024*2 = 4 x 8388608
    ushort_t* hf0 = (ushort_t*)(hbase);
    ushort_t* hf1 = (ushort_t*)(hbase + 8388608);
    ushort_t* hb0 = (ushort_t*)(hbase + 2 * 8388608);
    ushort_t* hb1 = (ushort_t*)(hbase + 3 * 8388608);

    // zero all 4 h buffers (33.5 MB)
    zero_kernel<<<8192, 256, 0, stream>>>((float4*)hbase, 2097152);
    precomp_P<<<3 * VN, 256, 0, stream>>>(src_emb, tgt_emb, Wf, bf, Wb, bb, Wd, bd, Pf, Pb, Pd);
    precomp_Bt<<<3 * GN, 256, 0, stream>>>(Uf, Ub, Ud, BtF, BtB, BtD);
    precomp_Wot<<<VN, 256, 0, stream>>>(Wo, Wot);

    // encoder: both directions per launch; 128-row tiles, grid (32,8,2) -> XCD=row-pin
    for (int t = 0; t < SN; t++) {
        const ushort_t* hfi = (t & 1) ? hf1 : hf0; ushort_t* hfo = (t & 1) ? hf0 : hf1;
        const ushort_t* hbi = (t & 1) ? hb1 : hb0; ushort_t* hbo = (t & 1) ? hb0 : hb1;
        gru_step<128, 2, 2, 4><<<dim3(32, 8, 2), 256, 0, stream>>>(
            hfi, hfo, BtF, bf + GN, Pf, 0,
            hbi, hbo, BtB, bb + GN, Pb, 1,
            source, t);
    }
    // decoder init state into hb1 (free after encoder; finals are in hf0/hb0)
    dec_init<<<(BN_ * HN + 255) / 256, 256, 0, stream>>>(hf0, hb0, hb1);

    // decoder + per-step logits (ping-pong hb1 <-> hf1); 64-row tiles, grid (64,8)
    for (int t = 0; t < TN; t++) {
        const ushort_t* hdi = (t & 1) ? hf1 : hb1; ushort_t* hdo = (t & 1) ? hb1 : hf1;
        gru_step<64, 1, 4, 4><<<dim3(64, 8, 1), 256, 0, stream>>>(
            hdi, hdo, BtD, bd + GN, Pd, 2,
            nullptr, nullptr, nullptr, nullptr, nullptr, 0,
            targets, t);
        logits_mfma<<<dim3(64, 4), 256, 0, stream>>>(hdo, Wot, bo, out, t);
    }
}

// Round 7
// 3335.083 us; speedup vs baseline: 1.2724x; 1.2724x over previous
//
#include <hip/hip_runtime.h>
#include <math.h>

typedef unsigned short ushort_t;
typedef short bf16x8 __attribute__((ext_vector_type(8)));   // 8 bf16 = 4 VGPRs (MFMA A/B frag)
typedef float f32x4 __attribute__((ext_vector_type(4)));    // MFMA C/D frag

#define BN_ 4096
#define SN 24
#define TN 24
#define EN 128
#define HN 512
#define GN 1536
#define VN 256
#define BOW_ 1
#define HC 1024   // hcat row stride: [hi(512) | lo(512)]
// K-extended split GEMM, 48 chunks of 32:
//   kc  0..15: Ahi (k=kc*32)        x Uhi chunk kc
//   kc 16..31: Alo (k=512+(kc-16)*32) x Uhi chunk kc-16   (B reused!)
//   kc 32..47: Ahi (k=(kc-32)*32)   x Ulo chunk kc-16
// B dedup'd: 32 unique chunks [Uhi(16) | Ulo(16)], 3 MB/dir -> L2-resident/XCD.

__device__ __forceinline__ float bf2f(ushort_t u) {
    union { unsigned int i; float f; } v; v.i = ((unsigned int)u) << 16; return v.f;
}
__device__ __forceinline__ ushort_t f2bf(float f) {  // round-to-nearest-even
    union { float f; unsigned int i; } v; v.f = f;
    unsigned int r = (v.i + 0x7FFFu + ((v.i >> 16) & 1u)) >> 16;
    return (ushort_t)r;
}

// async global->LDS, 16B per lane. LDS dest = wave-uniform base + lane*16 (HW).
__device__ __forceinline__ void gload16(const void* g, void* l) {
    __builtin_amdgcn_global_load_lds(
        (const __attribute__((address_space(1))) unsigned int*)g,
        (__attribute__((address_space(3))) unsigned int*)l, 16, 0, 0);
}

template<int N> __device__ __forceinline__ void waitcnt_vm() {
    asm volatile("s_waitcnt vmcnt(%0)" :: "n"(N) : "memory");
}
__device__ __forceinline__ void barrier_() { asm volatile("s_barrier" ::: "memory"); }

__global__ void zero_kernel(float4* __restrict__ p, int n16) {
    int i = blockIdx.x * blockDim.x + threadIdx.x;
    if (i < n16) p[i] = make_float4(0.f, 0.f, 0.f, 0.f);
}

// P[mat] = emb @ W + b_input  for (Wf,src), (Wb,src), (Wd,tgt). One block per (mat,row).
__global__ void precomp_P(const float* __restrict__ src_emb, const float* __restrict__ tgt_emb,
                          const float* __restrict__ Wf, const float* __restrict__ bf,
                          const float* __restrict__ Wb, const float* __restrict__ bb,
                          const float* __restrict__ Wd, const float* __restrict__ bd,
                          float* __restrict__ Pf, float* __restrict__ Pb, float* __restrict__ Pd) {
    int mat = blockIdx.x / VN;
    int row = blockIdx.x % VN;
    const float* emb = (mat == 2) ? tgt_emb : src_emb;
    const float* W   = (mat == 0) ? Wf : (mat == 1) ? Wb : Wd;
    const float* bia = (mat == 0) ? bf : (mat == 1) ? bb : bd;
    float* P         = (mat == 0) ? Pf : (mat == 1) ? Pb : Pd;
    __shared__ float e[EN];
    for (int i = threadIdx.x; i < EN; i += blockDim.x) e[i] = emb[row * EN + i];
    __syncthreads();
    for (int c = threadIdx.x; c < GN; c += blockDim.x) {
        float s = bia[c];
#pragma unroll 8
        for (int k = 0; k < EN; k++) s += e[k] * W[k * GN + c];
        P[row * GN + c] = s;
    }
}

// Dedup'd chunk-contiguous B: Bt2[mat][chunk 0..31][gcol 0..1535][j 0..31]
//   chunk<16: bf16hi(U[chunk*32+j][gcol]); chunk>=16: bf16lo(U[(chunk-16)*32+j][gcol])
__global__ void precomp_Bt2(const float* __restrict__ Uf, const float* __restrict__ Ub,
                            const float* __restrict__ Ud,
                            ushort_t* __restrict__ BtF, ushort_t* __restrict__ BtB,
                            ushort_t* __restrict__ BtD) {
    int mat = blockIdx.x >> 5;
    int c   = blockIdx.x & 31;
    const float* U = (mat == 0) ? Uf : (mat == 1) ? Ub : Ud;
    ushort_t* Bt   = (mat == 0) ? BtF : (mat == 1) ? BtB : BtD;
    const int kb = (c < 16) ? c * 32 : (c - 16) * 32;
    for (int idx = threadIdx.x; idx < GN * 32; idx += blockDim.x) {
        int gcol = idx >> 5, j = idx & 31;
        float u = U[(kb + j) * GN + gcol];
        ushort_t hi = f2bf(u);
        Bt[((size_t)c * GN + gcol) * 32 + j] = (c >= 16) ? f2bf(u - bf2f(hi)) : hi;
    }
}

// Wot2[chunk 0..31][col 0..255][j 0..31], same hi/lo rule.
__global__ void precomp_Wot2(const float* __restrict__ Wo, ushort_t* __restrict__ Wot) {
    int c = blockIdx.x;  // 0..31
    const int kb = (c < 16) ? c * 32 : (c - 16) * 32;
    for (int idx = threadIdx.x; idx < VN * 32; idx += blockDim.x) {
        int col = idx >> 5, j = idx & 31;
        float u = Wo[(kb + j) * VN + col];
        ushort_t hi = f2bf(u);
        Wot[((size_t)c * VN + col) * 32 + j] = (c >= 16) ? f2bf(u - bf2f(hi)) : hi;
    }
}

// decoder init state = hf_final + hb_final, stored as hi/lo bf16 pair
__global__ void dec_init(const ushort_t* __restrict__ hf, const ushort_t* __restrict__ hb,
                         ushort_t* __restrict__ hd) {
    int i = blockIdx.x * blockDim.x + threadIdx.x;
    if (i >= BN_ * HN) return;
    int row = i >> 9, col = i & (HN - 1);
    float h = bf2f(hf[(size_t)row * HC + col]) + bf2f(hf[(size_t)row * HC + HN + col])
            + bf2f(hb[(size_t)row * HC + col]) + bf2f(hb[(size_t)row * HC + HN + col]);
    ushort_t hi = f2bf(h);
    hd[(size_t)row * HC + col] = hi;
    hd[(size_t)row * HC + HN + col] = f2bf(h - bf2f(hi));
}

// One GRU step via bf16 MFMA split GEMM, M-tile 64, 4 waves x (64 rows x 16 cols x 3 gates).
// DUAL (encoder): grid (128, 8). XCD = bx%8 (HW: linear%8, 128*by==0 mod 8).
//   dir = bx&4 (fwd on XCD 0-3, bwd on 4-7) -> per-XCD B = 3 MB dedup'd, L2-resident,
//   step-invariant. rtile = (bx>>3)*4 + (bx&3) -> rows pinned to XCD across steps,
//   h-state (2 MB/XCD) L2-local.  !DUAL (decoder): grid (64, 8), rtile = bx.
// Staging: global_load_lds 16B, both-sides XOR swizzle (r4-verified: 0 conflicts),
// chunk-contiguous B (each gload16 = 1 KB contiguous). PD=2, counted vmcnt.
template<bool DUAL>
__global__ __launch_bounds__(256, 4) void gru_step(
    const ushort_t* __restrict__ hA_in, ushort_t* __restrict__ hA_out,
    const ushort_t* __restrict__ BtA, const float* __restrict__ brA,
    const float* __restrict__ PA, int modeA,
    const ushort_t* __restrict__ hB_in, ushort_t* __restrict__ hB_out,
    const ushort_t* __restrict__ BtB, const float* __restrict__ brB,
    const float* __restrict__ PB, int modeB,
    const int* __restrict__ tok, int t) {
    const int bx = blockIdx.x;
    const ushort_t* hin; ushort_t* hout; const ushort_t* Bt; const float* brec; const float* P; int mode;
    int rtile;
    if constexpr (DUAL) {
        if ((bx & 4) == 0) { hin = hA_in; hout = hA_out; Bt = BtA; brec = brA; P = PA; mode = modeA; }
        else               { hin = hB_in; hout = hB_out; Bt = BtB; brec = brB; P = PB; mode = modeB; }
        rtile = (bx >> 3) * 4 + (bx & 3);
    } else {
        hin = hA_in; hout = hA_out; Bt = BtA; brec = brA; P = PA; mode = modeA;
        rtile = bx;
    }
    const int bm = rtile * 64;
    const int bj = blockIdx.y * 64;
    const int tid = threadIdx.x;
    const int lane = tid & 63;
    const int w = tid >> 6;

    __shared__ __align__(16) short Asm[2][64 * 32];
    __shared__ __align__(16) short Bsm[2][192 * 32];

    f32x4 acc[3][4];
#pragma unroll
    for (int g = 0; g < 3; g++)
#pragma unroll
        for (int i = 0; i < 4; i++) acc[g][i] = (f32x4){0.f, 0.f, 0.f, 0.f};

    const int fl = lane & 15;
    const int fke = (((lane >> 4) ^ ((lane >> 1) & 3)) * 8);    // swizzled read slot
    const int lr = lane >> 2;                                   // staging row in 16-row group
    const int lk = (((lane & 3) ^ ((lane >> 3) & 3)) * 8);      // swizzled global slot

    auto stage = [&](int buf, int kc) {
        const int agk = (kc < 16) ? (kc * 32) : (kc < 32) ? (512 + (kc - 16) * 32) : ((kc - 32) * 32);
        const int bkc = (kc < 16) ? kc : (kc - 16);
        const int r0a = w * 16;
        gload16(hin + (size_t)(bm + r0a + lr) * HC + agk + lk, &Asm[buf][r0a * 32]);
#pragma unroll
        for (int s = 0; s < 3; ++s) {
            const int r0 = w * 48 + s * 16;
            const int r = r0 + lr;
            const int gcol = ((r >> 6) << 9) + bj + (r & 63);
            gload16(Bt + ((size_t)bkc * GN + gcol) * 32 + lk, &Bsm[buf][r0 * 32]);
        }
    };

    auto compute = [&](int cur) {
        const short* Ab = Asm[cur];
        const short* Bb = Bsm[cur];
        bf16x8 af[4];
#pragma unroll
        for (int i = 0; i < 4; i++)
            af[i] = *(const bf16x8*)&Ab[(i * 16 + fl) * 32 + fke];
#pragma unroll
        for (int g = 0; g < 3; g++) {
            bf16x8 bfr = *(const bf16x8*)&Bb[(g * 64 + w * 16 + fl) * 32 + fke];
#pragma unroll
            for (int i = 0; i < 4; i++)
                acc[g][i] = __builtin_amdgcn_mfma_f32_16x16x32_bf16(af[i], bfr, acc[g][i], 0, 0, 0);
        }
    };

    stage(0, 0);
    for (int kc = 0; kc < 48; ++kc) {
        if (kc < 47) { stage((kc + 1) & 1, kc + 1); waitcnt_vm<4>(); }
        else         { waitcnt_vm<0>(); }
        barrier_();                       // buf[kc&1] ready for all waves
        compute(kc & 1);
        barrier_();                       // reads done -> next iter may overwrite
    }

    const int fq = lane >> 4;
#pragma unroll
    for (int i = 0; i < 4; i++) {
#pragma unroll
        for (int q = 0; q < 4; q++) {
            const int row = bm + i * 16 + fq * 4 + q;
            int idx;
            if (mode == 2) idx = (t == 0) ? BOW_ : tok[row * TN + (t - 1)];
            else           idx = tok[row * SN + ((mode == 0) ? t : (SN - 1 - t))];
            const float* Pr = P + (size_t)idx * GN;
            const int col = bj + w * 16 + fl;
            float rz = acc[0][i][q] + brec[col];
            float rr = acc[1][i][q] + brec[HN + col];
            float rh = acc[2][i][q] + brec[2 * HN + col];
            float z = 1.f / (1.f + expf(-(Pr[col] + rz)));
            float r = 1.f / (1.f + expf(-(Pr[HN + col] + rr)));
            float hh = tanhf(Pr[2 * HN + col] + r * rh);
            float ho = bf2f(hin[(size_t)row * HC + col]) + bf2f(hin[(size_t)row * HC + HN + col]);
            float hnew = z * ho + (1.f - z) * hh;
            ushort_t hib = f2bf(hnew);
            hout[(size_t)row * HC + col] = hib;
            hout[(size_t)row * HC + HN + col] = f2bf(hnew - bf2f(hib));
        }
    }
}

// logits[:, t, :] = hd @ Wo + bo, dedup'd split GEMM. 64x64 tiles, grid (64,4).
// Wot2 = 0.5 MB -> trivially L2-resident. PD=2, NST=2.
__global__ __launch_bounds__(256) void logits_mfma(
    const ushort_t* __restrict__ hin, const ushort_t* __restrict__ Wot,
    const float* __restrict__ bo, float* __restrict__ out, int t) {
    const int bm = blockIdx.x * 64;
    const int bn = blockIdx.y * 64;
    const int tid = threadIdx.x;
    const int lane = tid & 63;
    const int w = tid >> 6;

    __shared__ __align__(16) short Asm[2][64 * 32];
    __shared__ __align__(16) short Bsm[2][64 * 32];

    f32x4 acc[4];
#pragma unroll
    for (int i = 0; i < 4; i++) acc[i] = (f32x4){0.f, 0.f, 0.f, 0.f};

    const int fl = lane & 15;
    const int fke = (((lane >> 4) ^ ((lane >> 1) & 3)) * 8);
    const int lr = lane >> 2;
    const int lk = (((lane & 3) ^ ((lane >> 3) & 3)) * 8);

    auto stage = [&](int buf, int kc) {
        const int agk = (kc < 16) ? (kc * 32) : (kc < 32) ? (512 + (kc - 16) * 32) : ((kc - 32) * 32);
        const int bkc = (kc < 16) ? kc : (kc - 16);
        const int r0 = w * 16;
        gload16(hin + (size_t)(bm + r0 + lr) * HC + agk + lk, &Asm[buf][r0 * 32]);
        gload16(Wot + ((size_t)bkc * VN + bn + r0 + lr) * 32 + lk, &Bsm[buf][r0 * 32]);
    };

    auto compute = [&](int cur) {
        const short* Ab = Asm[cur];
        const short* Bb = Bsm[cur];
        bf16x8 bfr = *(const bf16x8*)&Bb[(w * 16 + fl) * 32 + fke];
#pragma unroll
        for (int i = 0; i < 4; i++) {
            bf16x8 af = *(const bf16x8*)&Ab[(i * 16 + fl) * 32 + fke];
            acc[i] = __builtin_amdgcn_mfma_f32_16x16x32_bf16(af, bfr, acc[i], 0, 0, 0);
        }
    };

    stage(0, 0);
    for (int kc = 0; kc < 48; ++kc) {
        if (kc < 47) { stage((kc + 1) & 1, kc + 1); waitcnt_vm<2>(); }
        else         { waitcnt_vm<0>(); }
        barrier_();
        compute(kc & 1);
        barrier_();
    }

    const int fq = lane >> 4;
#pragma unroll
    for (int i = 0; i < 4; i++) {
#pragma unroll
        for (int q = 0; q < 4; q++) {
            const int row = bm + i * 16 + fq * 4 + q;
            const int col = bn + w * 16 + fl;
            out[(size_t)row * (TN * VN) + t * VN + col] = acc[i][q] + bo[col];
        }
    }
}

extern "C" void kernel_launch(void* const* d_in, const int* in_sizes, int n_in,
                              void* d_out, int out_size, void* d_ws, size_t ws_size,
                              hipStream_t stream) {
    const int* source    = (const int*)d_in[0];
    const int* targets   = (const int*)d_in[1];
    const float* src_emb = (const float*)d_in[2];
    const float* tgt_emb = (const float*)d_in[3];
    const float* Wf = (const float*)d_in[4];
    const float* Uf = (const float*)d_in[5];
    const float* bf = (const float*)d_in[6];
    const float* Wb = (const float*)d_in[7];
    const float* Ub = (const float*)d_in[8];
    const float* bb = (const float*)d_in[9];
    const float* Wd = (const float*)d_in[10];
    const float* Ud = (const float*)d_in[11];
    const float* bd = (const float*)d_in[12];
    const float* Wo = (const float*)d_in[13];
    const float* bo = (const float*)d_in[14];
    float* out = (float*)d_out;

    char* ws = (char*)d_ws;
    ushort_t* BtF = (ushort_t*)(ws);                    // 32*1536*32*2 = 3145728 each
    ushort_t* BtB = (ushort_t*)(ws + 3145728);
    ushort_t* BtD = (ushort_t*)(ws + 2 * 3145728);
    ushort_t* Wot = (ushort_t*)(ws + 3 * 3145728);      // 32*256*32*2 = 524288
    float*    Pf  = (float*)   (ws + 3 * 3145728 + 524288);  // 3*256*1536*4 = 4718592
    float*    Pb  = Pf + VN * GN;
    float*    Pd  = Pb + VN * GN;
    char* hbase = ws + 3 * 3145728 + 524288 + 4718592;  // 4 x 4096*1024*2 = 4 x 8388608
    ushort_t* hf0 = (ushort_t*)(hbase);
    ushort_t* hf1 = (ushort_t*)(hbase + 8388608);
    ushort_t* hb0 = (ushort_t*)(hbase + 2 * 8388608);
    ushort_t* hb1 = (ushort_t*)(hbase + 3 * 8388608);

    // zero all 4 h buffers (33.5 MB)
    zero_kernel<<<8192, 256, 0, stream>>>((float4*)hbase, 2097152);
    precomp_P<<<3 * VN, 256, 0, stream>>>(src_emb, tgt_emb, Wf, bf, Wb, bb, Wd, bd, Pf, Pb, Pd);
    precomp_Bt2<<<96, 256, 0, stream>>>(Uf, Ub, Ud, BtF, BtB, BtD);
    precomp_Wot2<<<32, 256, 0, stream>>>(Wo, Wot);

    // encoder: grid (128,8): XCD 0-3 fwd, 4-7 bwd; rows pinned; 4 blocks/CU
    for (int t = 0; t < SN; t++) {
        const ushort_t* hfi = (t & 1) ? hf1 : hf0; ushort_t* hfo = (t & 1) ? hf0 : hf1;
        const ushort_t* hbi = (t & 1) ? hb1 : hb0; ushort_t* hbo = (t & 1) ? hb0 : hb1;
        gru_step<true><<<dim3(128, 8), 256, 0, stream>>>(
            hfi, hfo, BtF, bf + GN, Pf, 0,
            hbi, hbo, BtB, bb + GN, Pb, 1,
            source, t);
    }
    // decoder init state into hb1 (free after encoder; finals are in hf0/hb0)
    dec_init<<<(BN_ * HN + 255) / 256, 256, 0, stream>>>(hf0, hb0, hb1);

    // decoder + per-step logits (ping-pong hb1 <-> hf1)
    for (int t = 0; t < TN; t++) {
        const ushort_t* hdi = (t & 1) ? hf1 : hb1; ushort_t* hdo = (t & 1) ? hb1 : hf1;
        gru_step<false><<<dim3(64, 8), 256, 0, stream>>>(
            hdi, hdo, BtD, bd + GN, Pd, 2,
            nullptr, nullptr, nullptr, nullptr, nullptr, 0,
            targets, t);
        logits_mfma<<<dim3(64, 4), 256, 0, stream>>>(hdo, Wot, bo, out, t);
    }
}

// Round 8
// 2626.172 us; speedup vs baseline: 1.6158x; 1.2699x over previous
//
#include <hip/hip_runtime.h>
#include <math.h>

typedef unsigned short ushort_t;
typedef short bf16x8 __attribute__((ext_vector_type(8)));   // 8 bf16 = 4 VGPRs (MFMA A/B frag)
typedef float f32x4 __attribute__((ext_vector_type(4)));    // MFMA C/D frag

#define BN_ 4096
#define SN 24
#define TN 24
#define EN 128
#define HN 512
#define GN 1536
#define VN 256
#define BOW_ 1
#define HC 1024   // hcat row stride: [hi(512) | lo(512)]
// K-extended split GEMM, 48 chunks of 32:
//   kc  0..15: Ahi x Uhi chunk kc ; 16..31: Alo x Uhi chunk kc-16 ; 32..47: Ahi x Ulo chunk kc-32
// B dedup'd: 32 unique chunks [Uhi(16) | Ulo(16)], 3 MB/dir -> L2-resident/XCD.

__device__ __forceinline__ float bf2f(ushort_t u) {
    union { unsigned int i; float f; } v; v.i = ((unsigned int)u) << 16; return v.f;
}
__device__ __forceinline__ ushort_t f2bf(float f) {  // round-to-nearest-even
    union { float f; unsigned int i; } v; v.f = f;
    unsigned int r = (v.i + 0x7FFFu + ((v.i >> 16) & 1u)) >> 16;
    return (ushort_t)r;
}

__device__ __forceinline__ void gload16(const void* g, void* l) {
    __builtin_amdgcn_global_load_lds(
        (const __attribute__((address_space(1))) unsigned int*)g,
        (__attribute__((address_space(3))) unsigned int*)l, 16, 0, 0);
}

template<int N> __device__ __forceinline__ void waitcnt_vm() {
    asm volatile("s_waitcnt vmcnt(%0)" :: "n"(N) : "memory");
}
__device__ __forceinline__ void barrier_() { asm volatile("s_barrier" ::: "memory"); }

__global__ void zero_kernel(float4* __restrict__ p, int n16) {
    int i = blockIdx.x * blockDim.x + threadIdx.x;
    if (i < n16) p[i] = make_float4(0.f, 0.f, 0.f, 0.f);
}

// P[mat] = emb @ W + b_input
__global__ void precomp_P(const float* __restrict__ src_emb, const float* __restrict__ tgt_emb,
                          const float* __restrict__ Wf, const float* __restrict__ bf,
                          const float* __restrict__ Wb, const float* __restrict__ bb,
                          const float* __restrict__ Wd, const float* __restrict__ bd,
                          float* __restrict__ Pf, float* __restrict__ Pb, float* __restrict__ Pd) {
    int mat = blockIdx.x / VN;
    int row = blockIdx.x % VN;
    const float* emb = (mat == 2) ? tgt_emb : src_emb;
    const float* W   = (mat == 0) ? Wf : (mat == 1) ? Wb : Wd;
    const float* bia = (mat == 0) ? bf : (mat == 1) ? bb : bd;
    float* P         = (mat == 0) ? Pf : (mat == 1) ? Pb : Pd;
    __shared__ float e[EN];
    for (int i = threadIdx.x; i < EN; i += blockDim.x) e[i] = emb[row * EN + i];
    __syncthreads();
    for (int c = threadIdx.x; c < GN; c += blockDim.x) {
        float s = bia[c];
#pragma unroll 8
        for (int k = 0; k < EN; k++) s += e[k] * W[k * GN + c];
        P[row * GN + c] = s;
    }
}

// Dedup'd chunk-contiguous B: Bt2[mat][chunk 0..31][gcol 0..1535][j 0..31]
__global__ void precomp_Bt2(const float* __restrict__ Uf, const float* __restrict__ Ub,
                            const float* __restrict__ Ud,
                            ushort_t* __restrict__ BtF, ushort_t* __restrict__ BtB,
                            ushort_t* __restrict__ BtD) {
    int mat = blockIdx.x >> 5;
    int c   = blockIdx.x & 31;
    const float* U = (mat == 0) ? Uf : (mat == 1) ? Ub : Ud;
    ushort_t* Bt   = (mat == 0) ? BtF : (mat == 1) ? BtB : BtD;
    const int kb = (c < 16) ? c * 32 : (c - 16) * 32;
    for (int idx = threadIdx.x; idx < GN * 32; idx += blockDim.x) {
        int gcol = idx >> 5, j = idx & 31;
        float u = U[(kb + j) * GN + gcol];
        ushort_t hi = f2bf(u);
        Bt[((size_t)c * GN + gcol) * 32 + j] = (c >= 16) ? f2bf(u - bf2f(hi)) : hi;
    }
}

__global__ void precomp_Wot2(const float* __restrict__ Wo, ushort_t* __restrict__ Wot) {
    int c = blockIdx.x;  // 0..31
    const int kb = (c < 16) ? c * 32 : (c - 16) * 32;
    for (int idx = threadIdx.x; idx < VN * 32; idx += blockDim.x) {
        int col = idx >> 5, j = idx & 31;
        float u = Wo[(kb + j) * VN + col];
        ushort_t hi = f2bf(u);
        Wot[((size_t)c * VN + col) * 32 + j] = (c >= 16) ? f2bf(u - bf2f(hi)) : hi;
    }
}

__global__ void dec_init(const ushort_t* __restrict__ hf, const ushort_t* __restrict__ hb,
                         ushort_t* __restrict__ hd) {
    int i = blockIdx.x * blockDim.x + threadIdx.x;
    if (i >= BN_ * HN) return;
    int row = i >> 9, col = i & (HN - 1);
    float h = bf2f(hf[(size_t)row * HC + col]) + bf2f(hf[(size_t)row * HC + HN + col])
            + bf2f(hb[(size_t)row * HC + col]) + bf2f(hb[(size_t)row * HC + HN + col]);
    ushort_t hi = f2bf(h);
    hd[(size_t)row * HC + col] = hi;
    hd[(size_t)row * HC + HN + col] = f2bf(h - bf2f(hi));
}

// ===== Encoder step: both dirs, MT=128, 4 waves of 64x32 (NN=2). Grid (64,8). =====
// XCD = bx%8: dir = bx&4 (fwd XCD 0-3, bwd 4-7), rtile = (bx>>3)*4 + (bx&3).
// Per XCD: B 3 MB dedup'd (step-invariant) + 1024 rows h (2 MB) ~ L2.
// LDS: A 2x8KB + B 2x12KB = 40 KB, 2 blocks/CU. 2-barrier PD=2, vmcnt(5).
__global__ __launch_bounds__(256, 2) void enc_step(
    const ushort_t* __restrict__ hf_in, ushort_t* __restrict__ hf_out,
    const ushort_t* __restrict__ BtF, const float* __restrict__ brF, const float* __restrict__ Pf,
    const ushort_t* __restrict__ hb_in, ushort_t* __restrict__ hb_out,
    const ushort_t* __restrict__ BtB, const float* __restrict__ brB, const float* __restrict__ Pb,
    const int* __restrict__ src, int t) {
    const int bx = blockIdx.x;
    const ushort_t* hin; ushort_t* hout; const ushort_t* Bt; const float* brec; const float* P; int rev;
    if ((bx & 4) == 0) { hin = hf_in; hout = hf_out; Bt = BtF; brec = brF; P = Pf; rev = 0; }
    else               { hin = hb_in; hout = hb_out; Bt = BtB; brec = brB; P = Pb; rev = 1; }
    const int bm = ((bx >> 3) * 4 + (bx & 3)) * 128;
    const int bj = blockIdx.y * 64;
    const int tid = threadIdx.x;
    const int lane = tid & 63;
    const int w = tid >> 6;
    const int wr = w >> 1, wc = w & 1;

    __shared__ __align__(16) short Asm[2][128 * 32];
    __shared__ __align__(16) short Bsm[2][192 * 32];

    f32x4 acc[3][4][2];
#pragma unroll
    for (int g = 0; g < 3; g++)
#pragma unroll
        for (int i = 0; i < 4; i++)
#pragma unroll
            for (int n = 0; n < 2; n++) acc[g][i][n] = (f32x4){0.f, 0.f, 0.f, 0.f};

    const int fl = lane & 15;
    const int fke = (((lane >> 4) ^ ((lane >> 1) & 3)) * 8);    // swizzled read slot
    const int lr = lane >> 2;
    const int lk = (((lane & 3) ^ ((lane >> 3) & 3)) * 8);      // swizzled global slot

    auto stage = [&](int buf, int kc) {
        const int agk = (kc < 16) ? (kc * 32) : (kc < 32) ? (512 + (kc - 16) * 32) : ((kc - 32) * 32);
        const int bkc = (kc < 16) ? kc : (kc - 16);
#pragma unroll
        for (int s = 0; s < 2; ++s) {
            const int r0 = w * 32 + s * 16;
            gload16(hin + (size_t)(bm + r0 + lr) * HC + agk + lk, &Asm[buf][r0 * 32]);
        }
#pragma unroll
        for (int s = 0; s < 3; ++s) {
            const int r0 = w * 48 + s * 16;
            const int r = r0 + lr;
            const int gcol = ((r >> 6) << 9) + bj + (r & 63);
            gload16(Bt + ((size_t)bkc * GN + gcol) * 32 + lk, &Bsm[buf][r0 * 32]);
        }
    };

    auto compute = [&](int cur) {
        const short* Ab = Asm[cur];
        const short* Bb = Bsm[cur];
        bf16x8 af[4];
#pragma unroll
        for (int i = 0; i < 4; i++)
            af[i] = *(const bf16x8*)&Ab[(wr * 64 + i * 16 + fl) * 32 + fke];
#pragma unroll
        for (int g = 0; g < 3; g++) {
#pragma unroll
            for (int n = 0; n < 2; n++) {
                bf16x8 bfr = *(const bf16x8*)&Bb[(g * 64 + wc * 32 + n * 16 + fl) * 32 + fke];
#pragma unroll
                for (int i = 0; i < 4; i++)
                    acc[g][i][n] = __builtin_amdgcn_mfma_f32_16x16x32_bf16(af[i], bfr, acc[g][i][n], 0, 0, 0);
            }
        }
    };

    stage(0, 0);
    for (int kc = 0; kc < 48; ++kc) {
        if (kc < 47) { stage((kc + 1) & 1, kc + 1); waitcnt_vm<5>(); }
        else         { waitcnt_vm<0>(); }
        barrier_();
        compute(kc & 1);
        barrier_();
    }

    const int fq = lane >> 4;
#pragma unroll
    for (int i = 0; i < 4; i++) {
#pragma unroll
        for (int q = 0; q < 4; q++) {
            const int row = bm + wr * 64 + i * 16 + fq * 4 + q;
            const int idx = src[row * SN + (rev ? (SN - 1 - t) : t)];
            const float* Pr = P + (size_t)idx * GN;
#pragma unroll
            for (int n = 0; n < 2; n++) {
                const int col = bj + wc * 32 + n * 16 + fl;
                float rz = acc[0][i][n][q] + brec[col];
                float rr = acc[1][i][n][q] + brec[HN + col];
                float rh = acc[2][i][n][q] + brec[2 * HN + col];
                float z = 1.f / (1.f + expf(-(Pr[col] + rz)));
                float r = 1.f / (1.f + expf(-(Pr[HN + col] + rr)));
                float hh = tanhf(Pr[2 * HN + col] + r * rh);
                float ho = bf2f(hin[(size_t)row * HC + col]) + bf2f(hin[(size_t)row * HC + HN + col]);
                float hnew = z * ho + (1.f - z) * hh;
                ushort_t hib = f2bf(hnew);
                hout[(size_t)row * HC + col] = hib;
                hout[(size_t)row * HC + HN + col] = f2bf(hnew - bf2f(hib));
            }
        }
    }
}

// ===== Fused decoder step t + logits of step t-1 (independent reads of hin). =====
// Grid 768: bx<512 dec (rtile=bx&63 -> XCD=rtile%8, bj=(bx>>6)*64);
// bx>=512 logits on hin -> out[:, t-1, :] (skipped when t==0).
__global__ __launch_bounds__(256, 3) void dec_fused(
    const ushort_t* __restrict__ hin, ushort_t* __restrict__ hout,
    const ushort_t* __restrict__ BtD, const float* __restrict__ brD, const float* __restrict__ Pd,
    const int* __restrict__ tgt, const ushort_t* __restrict__ Wot,
    const float* __restrict__ bo, float* __restrict__ out, int t) {
    const int bx = blockIdx.x;
    const int tid = threadIdx.x;
    const int lane = tid & 63;
    const int w = tid >> 6;
    const int fl = lane & 15;
    const int fke = (((lane >> 4) ^ ((lane >> 1) & 3)) * 8);
    const int lr = lane >> 2;
    const int lk = (((lane & 3) ^ ((lane >> 3) & 3)) * 8);
    const int fq = lane >> 4;

    __shared__ __align__(16) short SM[2][256 * 32];   // dec: A 64 rows + B 192 rows

    if (bx < 512) {
        const int bm = (bx & 63) * 64;
        const int bj = (bx >> 6) * 64;

        f32x4 acc[3][4];
#pragma unroll
        for (int g = 0; g < 3; g++)
#pragma unroll
            for (int i = 0; i < 4; i++) acc[g][i] = (f32x4){0.f, 0.f, 0.f, 0.f};

        auto stage = [&](int buf, int kc) {
            const int agk = (kc < 16) ? (kc * 32) : (kc < 32) ? (512 + (kc - 16) * 32) : ((kc - 32) * 32);
            const int bkc = (kc < 16) ? kc : (kc - 16);
            const int r0a = w * 16;
            gload16(hin + (size_t)(bm + r0a + lr) * HC + agk + lk, &SM[buf][r0a * 32]);
#pragma unroll
            for (int s = 0; s < 3; ++s) {
                const int r0 = w * 48 + s * 16;
                const int r = r0 + lr;
                const int gcol = ((r >> 6) << 9) + bj + (r & 63);
                gload16(BtD + ((size_t)bkc * GN + gcol) * 32 + lk, &SM[buf][(64 + r0) * 32]);
            }
        };
        auto compute = [&](int cur) {
            const short* Ab = &SM[cur][0];
            const short* Bb = &SM[cur][64 * 32];
            bf16x8 af[4];
#pragma unroll
            for (int i = 0; i < 4; i++)
                af[i] = *(const bf16x8*)&Ab[(i * 16 + fl) * 32 + fke];
#pragma unroll
            for (int g = 0; g < 3; g++) {
                bf16x8 bfr = *(const bf16x8*)&Bb[(g * 64 + w * 16 + fl) * 32 + fke];
#pragma unroll
                for (int i = 0; i < 4; i++)
                    acc[g][i] = __builtin_amdgcn_mfma_f32_16x16x32_bf16(af[i], bfr, acc[g][i], 0, 0, 0);
            }
        };

        stage(0, 0);
        for (int kc = 0; kc < 48; ++kc) {
            if (kc < 47) { stage((kc + 1) & 1, kc + 1); waitcnt_vm<4>(); }
            else         { waitcnt_vm<0>(); }
            barrier_();
            compute(kc & 1);
            barrier_();
        }

#pragma unroll
        for (int i = 0; i < 4; i++) {
#pragma unroll
            for (int q = 0; q < 4; q++) {
                const int row = bm + i * 16 + fq * 4 + q;
                const int idx = (t == 0) ? BOW_ : tgt[row * TN + (t - 1)];
                const float* Pr = Pd + (size_t)idx * GN;
                const int col = bj + w * 16 + fl;
                float rz = acc[0][i][q] + brD[col];
                float rr = acc[1][i][q] + brD[HN + col];
                float rh = acc[2][i][q] + brD[2 * HN + col];
                float z = 1.f / (1.f + expf(-(Pr[col] + rz)));
                float r = 1.f / (1.f + expf(-(Pr[HN + col] + rr)));
                float hh = tanhf(Pr[2 * HN + col] + r * rh);
                float ho = bf2f(hin[(size_t)row * HC + col]) + bf2f(hin[(size_t)row * HC + HN + col]);
                float hnew = z * ho + (1.f - z) * hh;
                ushort_t hib = f2bf(hnew);
                hout[(size_t)row * HC + col] = hib;
                hout[(size_t)row * HC + HN + col] = f2bf(hnew - bf2f(hib));
            }
        }
    } else {
        if (t == 0) return;
        const int l = bx - 512;
        const int bm = (l & 63) * 64;
        const int bn = (l >> 6) * 64;

        f32x4 acc[4];
#pragma unroll
        for (int i = 0; i < 4; i++) acc[i] = (f32x4){0.f, 0.f, 0.f, 0.f};

        auto stage = [&](int buf, int kc) {
            const int agk = (kc < 16) ? (kc * 32) : (kc < 32) ? (512 + (kc - 16) * 32) : ((kc - 32) * 32);
            const int bkc = (kc < 16) ? kc : (kc - 16);
            const int r0 = w * 16;
            gload16(hin + (size_t)(bm + r0 + lr) * HC + agk + lk, &SM[buf][r0 * 32]);
            gload16(Wot + ((size_t)bkc * VN + bn + r0 + lr) * 32 + lk, &SM[buf][(64 + r0) * 32]);
        };
        auto compute = [&](int cur) {
            const short* Ab = &SM[cur][0];
            const short* Bb = &SM[cur][64 * 32];
            bf16x8 bfr = *(const bf16x8*)&Bb[(w * 16 + fl) * 32 + fke];
#pragma unroll
            for (int i = 0; i < 4; i++) {
                bf16x8 af = *(const bf16x8*)&Ab[(i * 16 + fl) * 32 + fke];
                acc[i] = __builtin_amdgcn_mfma_f32_16x16x32_bf16(af, bfr, acc[i], 0, 0, 0);
            }
        };

        stage(0, 0);
        for (int kc = 0; kc < 48; ++kc) {
            if (kc < 47) { stage((kc + 1) & 1, kc + 1); waitcnt_vm<2>(); }
            else         { waitcnt_vm<0>(); }
            barrier_();
            compute(kc & 1);
            barrier_();
        }

#pragma unroll
        for (int i = 0; i < 4; i++) {
#pragma unroll
            for (int q = 0; q < 4; q++) {
                const int row = bm + i * 16 + fq * 4 + q;
                const int col = bn + w * 16 + fl;
                out[(size_t)row * (TN * VN) + (t - 1) * VN + col] = acc[i][q] + bo[col];
            }
        }
    }
}

// standalone logits for the final decoder output (t = TN-1)
__global__ __launch_bounds__(256) void logits_mfma(
    const ushort_t* __restrict__ hin, const ushort_t* __restrict__ Wot,
    const float* __restrict__ bo, float* __restrict__ out, int t) {
    const int bm = blockIdx.x * 64;
    const int bn = blockIdx.y * 64;
    const int tid = threadIdx.x;
    const int lane = tid & 63;
    const int w = tid >> 6;

    __shared__ __align__(16) short Asm[2][64 * 32];
    __shared__ __align__(16) short Bsm[2][64 * 32];

    f32x4 acc[4];
#pragma unroll
    for (int i = 0; i < 4; i++) acc[i] = (f32x4){0.f, 0.f, 0.f, 0.f};

    const int fl = lane & 15;
    const int fke = (((lane >> 4) ^ ((lane >> 1) & 3)) * 8);
    const int lr = lane >> 2;
    const int lk = (((lane & 3) ^ ((lane >> 3) & 3)) * 8);

    auto stage = [&](int buf, int kc) {
        const int agk = (kc < 16) ? (kc * 32) : (kc < 32) ? (512 + (kc - 16) * 32) : ((kc - 32) * 32);
        const int bkc = (kc < 16) ? kc : (kc - 16);
        const int r0 = w * 16;
        gload16(hin + (size_t)(bm + r0 + lr) * HC + agk + lk, &Asm[buf][r0 * 32]);
        gload16(Wot + ((size_t)bkc * VN + bn + r0 + lr) * 32 + lk, &Bsm[buf][r0 * 32]);
    };
    auto compute = [&](int cur) {
        const short* Ab = Asm[cur];
        const short* Bb = Bsm[cur];
        bf16x8 bfr = *(const bf16x8*)&Bb[(w * 16 + fl) * 32 + fke];
#pragma unroll
        for (int i = 0; i < 4; i++) {
            bf16x8 af = *(const bf16x8*)&Ab[(i * 16 + fl) * 32 + fke];
            acc[i] = __builtin_amdgcn_mfma_f32_16x16x32_bf16(af, bfr, acc[i], 0, 0, 0);
        }
    };

    stage(0, 0);
    for (int kc = 0; kc < 48; ++kc) {
        if (kc < 47) { stage((kc + 1) & 1, kc + 1); waitcnt_vm<2>(); }
        else         { waitcnt_vm<0>(); }
        barrier_();
        compute(kc & 1);
        barrier_();
    }

    const int fq = lane >> 4;
#pragma unroll
    for (int i = 0; i < 4; i++) {
#pragma unroll
        for (int q = 0; q < 4; q++) {
            const int row = bm + i * 16 + fq * 4 + q;
            const int col = bn + w * 16 + fl;
            out[(size_t)row * (TN * VN) + t * VN + col] = acc[i][q] + bo[col];
        }
    }
}

extern "C" void kernel_launch(void* const* d_in, const int* in_sizes, int n_in,
                              void* d_out, int out_size, void* d_ws, size_t ws_size,
                              hipStream_t stream) {
    const int* source    = (const int*)d_in[0];
    const int* targets   = (const int*)d_in[1];
    const float* src_emb = (const float*)d_in[2];
    const float* tgt_emb = (const float*)d_in[3];
    const float* Wf = (const float*)d_in[4];
    const float* Uf = (const float*)d_in[5];
    const float* bf = (const float*)d_in[6];
    const float* Wb = (const float*)d_in[7];
    const float* Ub = (const float*)d_in[8];
    const float* bb = (const float*)d_in[9];
    const float* Wd = (const float*)d_in[10];
    const float* Ud = (const float*)d_in[11];
    const float* bd = (const float*)d_in[12];
    const float* Wo = (const float*)d_in[13];
    const float* bo = (const float*)d_in[14];
    float* out = (float*)d_out;

    char* ws = (char*)d_ws;
    ushort_t* BtF = (ushort_t*)(ws);                    // 32*1536*32*2 = 3145728 each
    ushort_t* BtB = (ushort_t*)(ws + 3145728);
    ushort_t* BtD = (ushort_t*)(ws + 2 * 3145728);
    ushort_t* Wot = (ushort_t*)(ws + 3 * 3145728);      // 32*256*32*2 = 524288
    float*    Pf  = (float*)   (ws + 3 * 3145728 + 524288);  // 3*256*1536*4 = 4718592
    float*    Pb  = Pf + VN * GN;
    float*    Pd  = Pb + VN * GN;
    char* hbase = ws + 3 * 3145728 + 524288 + 4718592;  // 4 x 4096*1024*2 = 4 x 8388608
    ushort_t* hf0 = (ushort_t*)(hbase);
    ushort_t* hf1 = (ushort_t*)(hbase + 8388608);
    ushort_t* hb0 = (ushort_t*)(hbase + 2 * 8388608);
    ushort_t* hb1 = (ushort_t*)(hbase + 3 * 8388608);

    zero_kernel<<<8192, 256, 0, stream>>>((float4*)hbase, 2097152);
    precomp_P<<<3 * VN, 256, 0, stream>>>(src_emb, tgt_emb, Wf, bf, Wb, bb, Wd, bd, Pf, Pb, Pd);
    precomp_Bt2<<<96, 256, 0, stream>>>(Uf, Ub, Ud, BtF, BtB, BtD);
    precomp_Wot2<<<32, 256, 0, stream>>>(Wo, Wot);

    // encoder: grid (64,8): XCD 0-3 fwd / 4-7 bwd, 128-row tiles, 2 blocks/CU
    for (int t = 0; t < SN; t++) {
        const ushort_t* hfi = (t & 1) ? hf1 : hf0; ushort_t* hfo = (t & 1) ? hf0 : hf1;
        const ushort_t* hbi = (t & 1) ? hb1 : hb0; ushort_t* hbo = (t & 1) ? hb0 : hb1;
        enc_step<<<dim3(64, 8), 256, 0, stream>>>(
            hfi, hfo, BtF, bf + GN, Pf,
            hbi, hbo, BtB, bb + GN, Pb,
            source, t);
    }
    dec_init<<<(BN_ * HN + 255) / 256, 256, 0, stream>>>(hf0, hb0, hb1);

    // fused decoder step t + logits(t-1); ping-pong hb1 <-> hf1
    for (int t = 0; t < TN; t++) {
        const ushort_t* hdi = (t & 1) ? hf1 : hb1; ushort_t* hdo = (t & 1) ? hb1 : hf1;
        dec_fused<<<768, 256, 0, stream>>>(
            hdi, hdo, BtD, bd + GN, Pd, targets, Wot, bo, out, t);
    }
    // final logits for t = 23 output (hdo of t=23 is hb1 since 23 is odd)
    logits_mfma<<<dim3(64, 4), 256, 0, stream>>>(hb1, Wot, bo, out, TN - 1);
}

// Round 9
// 2157.139 us; speedup vs baseline: 1.9672x; 1.2174x over previous
//
#include <hip/hip_runtime.h>
#include <math.h>

typedef unsigned short ushort_t;
typedef short bf16x8 __attribute__((ext_vector_type(8)));   // 8 bf16 = 4 VGPRs (MFMA A/B frag)
typedef float f32x4 __attribute__((ext_vector_type(4)));    // MFMA C/D frag

#define BN_ 4096
#define SN 24
#define TN 24
#define EN 128
#define HN 512
#define GN 1536
#define VN 256
#define BOW_ 1
#define HC 1024   // hcat row stride: [hi(512) | lo(512)]
// Recurrent GEMMs (enc/dec): 2-term split, 32 chunks of 32:
//   kc 0..15:  Ahi (k=kc*32)          x Uhi chunk kc
//   kc 16..31: Alo (k=512+(kc-16)*32) x Uhi chunk kc-16   (B reused; = exact-h x bf16(U))
// Logits keeps the 3-term split (48 chunks) since it feeds the output directly.

__device__ __forceinline__ float bf2f(ushort_t u) {
    union { unsigned int i; float f; } v; v.i = ((unsigned int)u) << 16; return v.f;
}
__device__ __forceinline__ ushort_t f2bf(float f) {  // round-to-nearest-even
    union { float f; unsigned int i; } v; v.f = f;
    unsigned int r = (v.i + 0x7FFFu + ((v.i >> 16) & 1u)) >> 16;
    return (ushort_t)r;
}

__device__ __forceinline__ void gload16(const void* g, void* l) {
    __builtin_amdgcn_global_load_lds(
        (const __attribute__((address_space(1))) unsigned int*)g,
        (__attribute__((address_space(3))) unsigned int*)l, 16, 0, 0);
}

template<int N> __device__ __forceinline__ void waitcnt_vm() {
    asm volatile("s_waitcnt vmcnt(%0)" :: "n"(N) : "memory");
}
__device__ __forceinline__ void barrier_() { asm volatile("s_barrier" ::: "memory"); }

__global__ void zero_kernel(float4* __restrict__ p, int n16) {
    int i = blockIdx.x * blockDim.x + threadIdx.x;
    if (i < n16) p[i] = make_float4(0.f, 0.f, 0.f, 0.f);
}

// P[mat] = emb @ W + b_input
__global__ void precomp_P(const float* __restrict__ src_emb, const float* __restrict__ tgt_emb,
                          const float* __restrict__ Wf, const float* __restrict__ bf,
                          const float* __restrict__ Wb, const float* __restrict__ bb,
                          const float* __restrict__ Wd, const float* __restrict__ bd,
                          float* __restrict__ Pf, float* __restrict__ Pb, float* __restrict__ Pd) {
    int mat = blockIdx.x / VN;
    int row = blockIdx.x % VN;
    const float* emb = (mat == 2) ? tgt_emb : src_emb;
    const float* W   = (mat == 0) ? Wf : (mat == 1) ? Wb : Wd;
    const float* bia = (mat == 0) ? bf : (mat == 1) ? bb : bd;
    float* P         = (mat == 0) ? Pf : (mat == 1) ? Pb : Pd;
    __shared__ float e[EN];
    for (int i = threadIdx.x; i < EN; i += blockDim.x) e[i] = emb[row * EN + i];
    __syncthreads();
    for (int c = threadIdx.x; c < GN; c += blockDim.x) {
        float s = bia[c];
#pragma unroll 8
        for (int k = 0; k < EN; k++) s += e[k] * W[k * GN + c];
        P[row * GN + c] = s;
    }
}

// Recurrent B (hi only): Bt2[mat][chunk 0..15][gcol 0..1535][j 0..31] = bf16hi(U[chunk*32+j][gcol])
__global__ void precomp_Bt2(const float* __restrict__ Uf, const float* __restrict__ Ub,
                            const float* __restrict__ Ud,
                            ushort_t* __restrict__ BtF, ushort_t* __restrict__ BtB,
                            ushort_t* __restrict__ BtD) {
    int mat = blockIdx.x >> 4;
    int c   = blockIdx.x & 15;
    const float* U = (mat == 0) ? Uf : (mat == 1) ? Ub : Ud;
    ushort_t* Bt   = (mat == 0) ? BtF : (mat == 1) ? BtB : BtD;
    const int kb = c * 32;
    for (int idx = threadIdx.x; idx < GN * 32; idx += blockDim.x) {
        int gcol = idx >> 5, j = idx & 31;
        Bt[((size_t)c * GN + gcol) * 32 + j] = f2bf(U[(kb + j) * GN + gcol]);
    }
}

// Logits B (3-term): Wot2[chunk 0..31][col][j]; chunk<16 hi, >=16 lo.
__global__ void precomp_Wot2(const float* __restrict__ Wo, ushort_t* __restrict__ Wot) {
    int c = blockIdx.x;  // 0..31
    const int kb = (c < 16) ? c * 32 : (c - 16) * 32;
    for (int idx = threadIdx.x; idx < VN * 32; idx += blockDim.x) {
        int col = idx >> 5, j = idx & 31;
        float u = Wo[(kb + j) * VN + col];
        ushort_t hi = f2bf(u);
        Wot[((size_t)c * VN + col) * 32 + j] = (c >= 16) ? f2bf(u - bf2f(hi)) : hi;
    }
}

__global__ void dec_init(const ushort_t* __restrict__ hf, const ushort_t* __restrict__ hb,
                         ushort_t* __restrict__ hd) {
    int i = blockIdx.x * blockDim.x + threadIdx.x;
    if (i >= BN_ * HN) return;
    int row = i >> 9, col = i & (HN - 1);
    float h = bf2f(hf[(size_t)row * HC + col]) + bf2f(hf[(size_t)row * HC + HN + col])
            + bf2f(hb[(size_t)row * HC + col]) + bf2f(hb[(size_t)row * HC + HN + col]);
    ushort_t hi = f2bf(h);
    hd[(size_t)row * HC + col] = hi;
    hd[(size_t)row * HC + HN + col] = f2bf(h - bf2f(hi));
}

// ===== Encoder step: both dirs, MT=128, 4 waves of 64x32 (NN=2). Grid (64,8). =====
// XCD = bx%8: dir = bx&4 (fwd XCD 0-3, bwd 4-7), rtile = (bx>>3)*4 + (bx&3).
// Per XCD: B 1.5 MB (step-invariant, L2-resident) + 1024 rows h (2 MB) L2-local.
// 32 chunks (2-term split). LDS 40 KB, 2 blocks/CU. PD=2, counted vmcnt(5).
__global__ __launch_bounds__(256, 2) void enc_step(
    const ushort_t* __restrict__ hf_in, ushort_t* __restrict__ hf_out,
    const ushort_t* __restrict__ BtF, const float* __restrict__ brF, const float* __restrict__ Pf,
    const ushort_t* __restrict__ hb_in, ushort_t* __restrict__ hb_out,
    const ushort_t* __restrict__ BtB, const float* __restrict__ brB, const float* __restrict__ Pb,
    const int* __restrict__ src, int t) {
    const int bx = blockIdx.x;
    const ushort_t* hin; ushort_t* hout; const ushort_t* Bt; const float* brec; const float* P; int rev;
    if ((bx & 4) == 0) { hin = hf_in; hout = hf_out; Bt = BtF; brec = brF; P = Pf; rev = 0; }
    else               { hin = hb_in; hout = hb_out; Bt = BtB; brec = brB; P = Pb; rev = 1; }
    const int bm = ((bx >> 3) * 4 + (bx & 3)) * 128;
    const int bj = blockIdx.y * 64;
    const int tid = threadIdx.x;
    const int lane = tid & 63;
    const int w = tid >> 6;
    const int wr = w >> 1, wc = w & 1;

    __shared__ __align__(16) short Asm[2][128 * 32];
    __shared__ __align__(16) short Bsm[2][192 * 32];

    f32x4 acc[3][4][2];
#pragma unroll
    for (int g = 0; g < 3; g++)
#pragma unroll
        for (int i = 0; i < 4; i++)
#pragma unroll
            for (int n = 0; n < 2; n++) acc[g][i][n] = (f32x4){0.f, 0.f, 0.f, 0.f};

    const int fl = lane & 15;
    const int fke = (((lane >> 4) ^ ((lane >> 1) & 3)) * 8);    // swizzled read slot
    const int lr = lane >> 2;
    const int lk = (((lane & 3) ^ ((lane >> 3) & 3)) * 8);      // swizzled global slot

    auto stage = [&](int buf, int kc) {
        const int agk = (kc < 16) ? (kc * 32) : (512 + (kc - 16) * 32);
        const int bkc = kc & 15;
#pragma unroll
        for (int s = 0; s < 2; ++s) {
            const int r0 = w * 32 + s * 16;
            gload16(hin + (size_t)(bm + r0 + lr) * HC + agk + lk, &Asm[buf][r0 * 32]);
        }
#pragma unroll
        for (int s = 0; s < 3; ++s) {
            const int r0 = w * 48 + s * 16;
            const int r = r0 + lr;
            const int gcol = ((r >> 6) << 9) + bj + (r & 63);
            gload16(Bt + ((size_t)bkc * GN + gcol) * 32 + lk, &Bsm[buf][r0 * 32]);
        }
    };

    auto compute = [&](int cur) {
        const short* Ab = Asm[cur];
        const short* Bb = Bsm[cur];
        bf16x8 af[4];
#pragma unroll
        for (int i = 0; i < 4; i++)
            af[i] = *(const bf16x8*)&Ab[(wr * 64 + i * 16 + fl) * 32 + fke];
#pragma unroll
        for (int g = 0; g < 3; g++) {
#pragma unroll
            for (int n = 0; n < 2; n++) {
                bf16x8 bfr = *(const bf16x8*)&Bb[(g * 64 + wc * 32 + n * 16 + fl) * 32 + fke];
#pragma unroll
                for (int i = 0; i < 4; i++)
                    acc[g][i][n] = __builtin_amdgcn_mfma_f32_16x16x32_bf16(af[i], bfr, acc[g][i][n], 0, 0, 0);
            }
        }
    };

    stage(0, 0);
    for (int kc = 0; kc < 32; ++kc) {
        if (kc < 31) { stage((kc + 1) & 1, kc + 1); waitcnt_vm<5>(); }
        else         { waitcnt_vm<0>(); }
        barrier_();
        compute(kc & 1);
        barrier_();
    }

    const int fq = lane >> 4;
#pragma unroll
    for (int i = 0; i < 4; i++) {
#pragma unroll
        for (int q = 0; q < 4; q++) {
            const int row = bm + wr * 64 + i * 16 + fq * 4 + q;
            const int idx = src[row * SN + (rev ? (SN - 1 - t) : t)];
            const float* Pr = P + (size_t)idx * GN;
#pragma unroll
            for (int n = 0; n < 2; n++) {
                const int col = bj + wc * 32 + n * 16 + fl;
                float rz = acc[0][i][n][q] + brec[col];
                float rr = acc[1][i][n][q] + brec[HN + col];
                float rh = acc[2][i][n][q] + brec[2 * HN + col];
                float z = 1.f / (1.f + expf(-(Pr[col] + rz)));
                float r = 1.f / (1.f + expf(-(Pr[HN + col] + rr)));
                float hh = tanhf(Pr[2 * HN + col] + r * rh);
                float ho = bf2f(hin[(size_t)row * HC + col]) + bf2f(hin[(size_t)row * HC + HN + col]);
                float hnew = z * ho + (1.f - z) * hh;
                ushort_t hib = f2bf(hnew);
                hout[(size_t)row * HC + col] = hib;
                hout[(size_t)row * HC + HN + col] = f2bf(hnew - bf2f(hib));
            }
        }
    }
}

// ===== Fused decoder step t (32 chunks) + logits of step t-1 (48 chunks, 3-term). =====
__global__ __launch_bounds__(256, 3) void dec_fused(
    const ushort_t* __restrict__ hin, ushort_t* __restrict__ hout,
    const ushort_t* __restrict__ BtD, const float* __restrict__ brD, const float* __restrict__ Pd,
    const int* __restrict__ tgt, const ushort_t* __restrict__ Wot,
    const float* __restrict__ bo, float* __restrict__ out, int t) {
    const int bx = blockIdx.x;
    const int tid = threadIdx.x;
    const int lane = tid & 63;
    const int w = tid >> 6;
    const int fl = lane & 15;
    const int fke = (((lane >> 4) ^ ((lane >> 1) & 3)) * 8);
    const int lr = lane >> 2;
    const int lk = (((lane & 3) ^ ((lane >> 3) & 3)) * 8);
    const int fq = lane >> 4;

    __shared__ __align__(16) short SM[2][256 * 32];   // dec: A 64 rows + B 192 rows

    if (bx < 512) {
        const int bm = (bx & 63) * 64;
        const int bj = (bx >> 6) * 64;

        f32x4 acc[3][4];
#pragma unroll
        for (int g = 0; g < 3; g++)
#pragma unroll
            for (int i = 0; i < 4; i++) acc[g][i] = (f32x4){0.f, 0.f, 0.f, 0.f};

        auto stage = [&](int buf, int kc) {
            const int agk = (kc < 16) ? (kc * 32) : (512 + (kc - 16) * 32);
            const int bkc = kc & 15;
            const int r0a = w * 16;
            gload16(hin + (size_t)(bm + r0a + lr) * HC + agk + lk, &SM[buf][r0a * 32]);
#pragma unroll
            for (int s = 0; s < 3; ++s) {
                const int r0 = w * 48 + s * 16;
                const int r = r0 + lr;
                const int gcol = ((r >> 6) << 9) + bj + (r & 63);
                gload16(BtD + ((size_t)bkc * GN + gcol) * 32 + lk, &SM[buf][(64 + r0) * 32]);
            }
        };
        auto compute = [&](int cur) {
            const short* Ab = &SM[cur][0];
            const short* Bb = &SM[cur][64 * 32];
            bf16x8 af[4];
#pragma unroll
            for (int i = 0; i < 4; i++)
                af[i] = *(const bf16x8*)&Ab[(i * 16 + fl) * 32 + fke];
#pragma unroll
            for (int g = 0; g < 3; g++) {
                bf16x8 bfr = *(const bf16x8*)&Bb[(g * 64 + w * 16 + fl) * 32 + fke];
#pragma unroll
                for (int i = 0; i < 4; i++)
                    acc[g][i] = __builtin_amdgcn_mfma_f32_16x16x32_bf16(af[i], bfr, acc[g][i], 0, 0, 0);
            }
        };

        stage(0, 0);
        for (int kc = 0; kc < 32; ++kc) {
            if (kc < 31) { stage((kc + 1) & 1, kc + 1); waitcnt_vm<4>(); }
            else         { waitcnt_vm<0>(); }
            barrier_();
            compute(kc & 1);
            barrier_();
        }

#pragma unroll
        for (int i = 0; i < 4; i++) {
#pragma unroll
            for (int q = 0; q < 4; q++) {
                const int row = bm + i * 16 + fq * 4 + q;
                const int idx = (t == 0) ? BOW_ : tgt[row * TN + (t - 1)];
                const float* Pr = Pd + (size_t)idx * GN;
                const int col = bj + w * 16 + fl;
                float rz = acc[0][i][q] + brD[col];
                float rr = acc[1][i][q] + brD[HN + col];
                float rh = acc[2][i][q] + brD[2 * HN + col];
                float z = 1.f / (1.f + expf(-(Pr[col] + rz)));
                float r = 1.f / (1.f + expf(-(Pr[HN + col] + rr)));
                float hh = tanhf(Pr[2 * HN + col] + r * rh);
                float ho = bf2f(hin[(size_t)row * HC + col]) + bf2f(hin[(size_t)row * HC + HN + col]);
                float hnew = z * ho + (1.f - z) * hh;
                ushort_t hib = f2bf(hnew);
                hout[(size_t)row * HC + col] = hib;
                hout[(size_t)row * HC + HN + col] = f2bf(hnew - bf2f(hib));
            }
        }
    } else {
        if (t == 0) return;
        const int l = bx - 512;
        const int bm = (l & 63) * 64;
        const int bn = (l >> 6) * 64;

        f32x4 acc[4];
#pragma unroll
        for (int i = 0; i < 4; i++) acc[i] = (f32x4){0.f, 0.f, 0.f, 0.f};

        auto stage = [&](int buf, int kc) {
            const int agk = (kc < 16) ? (kc * 32) : (kc < 32) ? (512 + (kc - 16) * 32) : ((kc - 32) * 32);
            const int bkc = (kc < 16) ? kc : (kc - 16);
            const int r0 = w * 16;
            gload16(hin + (size_t)(bm + r0 + lr) * HC + agk + lk, &SM[buf][r0 * 32]);
            gload16(Wot + ((size_t)bkc * VN + bn + r0 + lr) * 32 + lk, &SM[buf][(64 + r0) * 32]);
        };
        auto compute = [&](int cur) {
            const short* Ab = &SM[cur][0];
            const short* Bb = &SM[cur][64 * 32];
            bf16x8 bfr = *(const bf16x8*)&Bb[(w * 16 + fl) * 32 + fke];
#pragma unroll
            for (int i = 0; i < 4; i++) {
                bf16x8 af = *(const bf16x8*)&Ab[(i * 16 + fl) * 32 + fke];
                acc[i] = __builtin_amdgcn_mfma_f32_16x16x32_bf16(af, bfr, acc[i], 0, 0, 0);
            }
        };

        stage(0, 0);
        for (int kc = 0; kc < 48; ++kc) {
            if (kc < 47) { stage((kc + 1) & 1, kc + 1); waitcnt_vm<2>(); }
            else         { waitcnt_vm<0>(); }
            barrier_();
            compute(kc & 1);
            barrier_();
        }

#pragma unroll
        for (int i = 0; i < 4; i++) {
#pragma unroll
            for (int q = 0; q < 4; q++) {
                const int row = bm + i * 16 + fq * 4 + q;
                const int col = bn + w * 16 + fl;
                out[(size_t)row * (TN * VN) + (t - 1) * VN + col] = acc[i][q] + bo[col];
            }
        }
    }
}

// standalone logits for the final decoder output (t = TN-1), 3-term split
__global__ __launch_bounds__(256) void logits_mfma(
    const ushort_t* __restrict__ hin, const ushort_t* __restrict__ Wot,
    const float* __restrict__ bo, float* __restrict__ out, int t) {
    const int bm = blockIdx.x * 64;
    const int bn = blockIdx.y * 64;
    const int tid = threadIdx.x;
    const int lane = tid & 63;
    const int w = tid >> 6;

    __shared__ __align__(16) short Asm[2][64 * 32];
    __shared__ __align__(16) short Bsm[2][64 * 32];

    f32x4 acc[4];
#pragma unroll
    for (int i = 0; i < 4; i++) acc[i] = (f32x4){0.f, 0.f, 0.f, 0.f};

    const int fl = lane & 15;
    const int fke = (((lane >> 4) ^ ((lane >> 1) & 3)) * 8);
    const int lr = lane >> 2;
    const int lk = (((lane & 3) ^ ((lane >> 3) & 3)) * 8);

    auto stage = [&](int buf, int kc) {
        const int agk = (kc < 16) ? (kc * 32) : (kc < 32) ? (512 + (kc - 16) * 32) : ((kc - 32) * 32);
        const int bkc = (kc < 16) ? kc : (kc - 16);
        const int r0 = w * 16;
        gload16(hin + (size_t)(bm + r0 + lr) * HC + agk + lk, &Asm[buf][r0 * 32]);
        gload16(Wot + ((size_t)bkc * VN + bn + r0 + lr) * 32 + lk, &Bsm[buf][r0 * 32]);
    };
    auto compute = [&](int cur) {
        const short* Ab = Asm[cur];
        const short* Bb = Bsm[cur];
        bf16x8 bfr = *(const bf16x8*)&Bb[(w * 16 + fl) * 32 + fke];
#pragma unroll
        for (int i = 0; i < 4; i++) {
            bf16x8 af = *(const bf16x8*)&Ab[(i * 16 + fl) * 32 + fke];
            acc[i] = __builtin_amdgcn_mfma_f32_16x16x32_bf16(af, bfr, acc[i], 0, 0, 0);
        }
    };

    stage(0, 0);
    for (int kc = 0; kc < 48; ++kc) {
        if (kc < 47) { stage((kc + 1) & 1, kc + 1); waitcnt_vm<2>(); }
        else         { waitcnt_vm<0>(); }
        barrier_();
        compute(kc & 1);
        barrier_();
    }

    const int fq = lane >> 4;
#pragma unroll
    for (int i = 0; i < 4; i++) {
#pragma unroll
        for (int q = 0; q < 4; q++) {
            const int row = bm + i * 16 + fq * 4 + q;
            const int col = bn + w * 16 + fl;
            out[(size_t)row * (TN * VN) + t * VN + col] = acc[i][q] + bo[col];
        }
    }
}

extern "C" void kernel_launch(void* const* d_in, const int* in_sizes, int n_in,
                              void* d_out, int out_size, void* d_ws, size_t ws_size,
                              hipStream_t stream) {
    const int* source    = (const int*)d_in[0];
    const int* targets   = (const int*)d_in[1];
    const float* src_emb = (const float*)d_in[2];
    const float* tgt_emb = (const float*)d_in[3];
    const float* Wf = (const float*)d_in[4];
    const float* Uf = (const float*)d_in[5];
    const float* bf = (const float*)d_in[6];
    const float* Wb = (const float*)d_in[7];
    const float* Ub = (const float*)d_in[8];
    const float* bb = (const float*)d_in[9];
    const float* Wd = (const float*)d_in[10];
    const float* Ud = (const float*)d_in[11];
    const float* bd = (const float*)d_in[12];
    const float* Wo = (const float*)d_in[13];
    const float* bo = (const float*)d_in[14];
    float* out = (float*)d_out;

    char* ws = (char*)d_ws;
    ushort_t* BtF = (ushort_t*)(ws);                    // 16*1536*32*2 = 1572864 each
    ushort_t* BtB = (ushort_t*)(ws + 1572864);
    ushort_t* BtD = (ushort_t*)(ws + 2 * 1572864);
    ushort_t* Wot = (ushort_t*)(ws + 3 * 1572864);      // 32*256*32*2 = 524288
    float*    Pf  = (float*)   (ws + 3 * 1572864 + 524288);  // 3*256*1536*4 = 4718592
    float*    Pb  = Pf + VN * GN;
    float*    Pd  = Pb + VN * GN;
    char* hbase = ws + 3 * 1572864 + 524288 + 4718592;  // 4 x 4096*1024*2 = 4 x 8388608
    ushort_t* hf0 = (ushort_t*)(hbase);
    ushort_t* hf1 = (ushort_t*)(hbase + 8388608);
    ushort_t* hb0 = (ushort_t*)(hbase + 2 * 8388608);
    ushort_t* hb1 = (ushort_t*)(hbase + 3 * 8388608);

    zero_kernel<<<8192, 256, 0, stream>>>((float4*)hbase, 2097152);
    precomp_P<<<3 * VN, 256, 0, stream>>>(src_emb, tgt_emb, Wf, bf, Wb, bb, Wd, bd, Pf, Pb, Pd);
    precomp_Bt2<<<48, 256, 0, stream>>>(Uf, Ub, Ud, BtF, BtB, BtD);
    precomp_Wot2<<<32, 256, 0, stream>>>(Wo, Wot);

    // encoder: grid (64,8): XCD 0-3 fwd / 4-7 bwd, 128-row tiles, 2 blocks/CU
    for (int t = 0; t < SN; t++) {
        const ushort_t* hfi = (t & 1) ? hf1 : hf0; ushort_t* hfo = (t & 1) ? hf0 : hf1;
        const ushort_t* hbi = (t & 1) ? hb1 : hb0; ushort_t* hbo = (t & 1) ? hb0 : hb1;
        enc_step<<<dim3(64, 8), 256, 0, stream>>>(
            hfi, hfo, BtF, bf + GN, Pf,
            hbi, hbo, BtB, bb + GN, Pb,
            source, t);
    }
    dec_init<<<(BN_ * HN + 255) / 256, 256, 0, stream>>>(hf0, hb0, hb1);

    // fused decoder step t + logits(t-1); ping-pong hb1 <-> hf1
    for (int t = 0; t < TN; t++) {
        const ushort_t* hdi = (t & 1) ? hf1 : hb1; ushort_t* hdo = (t & 1) ? hb1 : hf1;
        dec_fused<<<768, 256, 0, stream>>>(
            hdi, hdo, BtD, bd + GN, Pd, targets, Wot, bo, out, t);
    }
    // final logits for t = 23 output (hdo of t=23 is hb1 since 23 is odd)
    logits_mfma<<<dim3(64, 4), 256, 0, stream>>>(hb1, Wot, bo, out, TN - 1);
}

// Round 10
// 2082.513 us; speedup vs baseline: 2.0376x; 1.0358x over previous
//
#include <hip/hip_runtime.h>
#include <math.h>

typedef unsigned short ushort_t;
typedef short bf16x8 __attribute__((ext_vector_type(8)));   // 8 bf16 = 4 VGPRs (MFMA A/B frag)
typedef float f32x4 __attribute__((ext_vector_type(4)));    // MFMA C/D frag

#define BN_ 4096
#define SN 24
#define TN 24
#define EN 128
#define HN 512
#define GN 1536
#define VN 256
#define BOW_ 1
#define HC 1024   // hcat row stride: [hi(512) | lo(512)]
// Recurrent GEMMs (enc/dec): 2-term split, 32 chunks of 32:
//   kc 0..15:  Ahi (k=kc*32)          x Uhi chunk kc
//   kc 16..31: Alo (k=512+(kc-16)*32) x Uhi chunk kc-16   (B reused; = exact-h x bf16(U))
// Logits keeps the 3-term split (48 chunks) since it feeds the output directly.

__device__ __forceinline__ float bf2f(ushort_t u) {
    union { unsigned int i; float f; } v; v.i = ((unsigned int)u) << 16; return v.f;
}
__device__ __forceinline__ ushort_t f2bf(float f) {  // round-to-nearest-even
    union { float f; unsigned int i; } v; v.f = f;
    unsigned int r = (v.i + 0x7FFFu + ((v.i >> 16) & 1u)) >> 16;
    return (ushort_t)r;
}

__device__ __forceinline__ void gload16(const void* g, void* l) {
    __builtin_amdgcn_global_load_lds(
        (const __attribute__((address_space(1))) unsigned int*)g,
        (__attribute__((address_space(3))) unsigned int*)l, 16, 0, 0);
}

template<int N> __device__ __forceinline__ void waitcnt_vm() {
    asm volatile("s_waitcnt vmcnt(%0)" :: "n"(N) : "memory");
}
__device__ __forceinline__ void barrier_() { asm volatile("s_barrier" ::: "memory"); }

__global__ void zero_kernel(float4* __restrict__ p, int n16) {
    int i = blockIdx.x * blockDim.x + threadIdx.x;
    if (i < n16) p[i] = make_float4(0.f, 0.f, 0.f, 0.f);
}

// ===== P = emb @ W + b_input, tiled (64x64 tiles, K=128 staged in LDS) =====
// grid (4, 24, 3): z = mat. W-tile reused across 64 rows; ~10 us total.
__global__ __launch_bounds__(256) void precomp_P(
    const float* __restrict__ src_emb, const float* __restrict__ tgt_emb,
    const float* __restrict__ Wf, const float* __restrict__ bf,
    const float* __restrict__ Wb, const float* __restrict__ bb,
    const float* __restrict__ Wd, const float* __restrict__ bd,
    float* __restrict__ Pf, float* __restrict__ Pb, float* __restrict__ Pd) {
    const int mat = blockIdx.z;
    const float* emb = (mat == 2) ? tgt_emb : src_emb;
    const float* W   = (mat == 0) ? Wf : (mat == 1) ? Wb : Wd;
    const float* bia = (mat == 0) ? bf : (mat == 1) ? bb : bd;
    float* P         = (mat == 0) ? Pf : (mat == 1) ? Pb : Pd;

    const int bm = blockIdx.x * 64;
    const int bn = blockIdx.y * 64;
    const int tid = threadIdx.x;
    const int tx = tid & 15;
    const int ty = tid >> 4;

    __shared__ __align__(16) float As[64][17];
    __shared__ __align__(16) float Bs[16][64];

    float acc[4][4];
#pragma unroll
    for (int i = 0; i < 4; i++)
#pragma unroll
        for (int j = 0; j < 4; j++) acc[i][j] = 0.0f;

    const int ar = tid >> 2;
    const int ak = (tid & 3) * 4;
    const int bk = tid >> 4;
    const int bc = (tid & 15) * 4;

    for (int k0 = 0; k0 < EN; k0 += 16) {
        float4 av = *reinterpret_cast<const float4*>(&emb[(bm + ar) * EN + k0 + ak]);
        As[ar][ak + 0] = av.x; As[ar][ak + 1] = av.y; As[ar][ak + 2] = av.z; As[ar][ak + 3] = av.w;
        float4 bv = *reinterpret_cast<const float4*>(&W[(k0 + bk) * GN + bn + bc]);
        *reinterpret_cast<float4*>(&Bs[bk][bc]) = bv;
        __syncthreads();
#pragma unroll
        for (int kk = 0; kk < 16; kk++) {
            float a[4];
#pragma unroll
            for (int i = 0; i < 4; i++) a[i] = As[ty * 4 + i][kk];
            float4 b4 = *reinterpret_cast<float4*>(&Bs[kk][tx * 4]);
#pragma unroll
            for (int i = 0; i < 4; i++) {
                acc[i][0] += a[i] * b4.x;
                acc[i][1] += a[i] * b4.y;
                acc[i][2] += a[i] * b4.z;
                acc[i][3] += a[i] * b4.w;
            }
        }
        __syncthreads();
    }

#pragma unroll
    for (int i = 0; i < 4; i++) {
        const int row = bm + ty * 4 + i;
#pragma unroll
        for (int j = 0; j < 4; j++) {
            const int col = bn + tx * 4 + j;
            P[(size_t)row * GN + col] = acc[i][j] + bia[col];
        }
    }
}

// Recurrent B (hi only): Bt2[mat][chunk 0..15][gcol 0..1535][j 0..31] = bf16hi(U[chunk*32+j][gcol])
__global__ void precomp_Bt2(const float* __restrict__ Uf, const float* __restrict__ Ub,
                            const float* __restrict__ Ud,
                            ushort_t* __restrict__ BtF, ushort_t* __restrict__ BtB,
                            ushort_t* __restrict__ BtD) {
    int mat = blockIdx.x >> 4;
    int c   = blockIdx.x & 15;
    const float* U = (mat == 0) ? Uf : (mat == 1) ? Ub : Ud;
    ushort_t* Bt   = (mat == 0) ? BtF : (mat == 1) ? BtB : BtD;
    const int kb = c * 32;
    for (int idx = threadIdx.x; idx < GN * 32; idx += blockDim.x) {
        int gcol = idx >> 5, j = idx & 31;
        Bt[((size_t)c * GN + gcol) * 32 + j] = f2bf(U[(kb + j) * GN + gcol]);
    }
}

// Logits B (3-term): Wot2[chunk 0..31][col][j]; chunk<16 hi, >=16 lo.
__global__ void precomp_Wot2(const float* __restrict__ Wo, ushort_t* __restrict__ Wot) {
    int c = blockIdx.x;  // 0..31
    const int kb = (c < 16) ? c * 32 : (c - 16) * 32;
    for (int idx = threadIdx.x; idx < VN * 32; idx += blockDim.x) {
        int col = idx >> 5, j = idx & 31;
        float u = Wo[(kb + j) * VN + col];
        ushort_t hi = f2bf(u);
        Wot[((size_t)c * VN + col) * 32 + j] = (c >= 16) ? f2bf(u - bf2f(hi)) : hi;
    }
}

__global__ void dec_init(const ushort_t* __restrict__ hf, const ushort_t* __restrict__ hb,
                         ushort_t* __restrict__ hd) {
    int i = blockIdx.x * blockDim.x + threadIdx.x;
    if (i >= BN_ * HN) return;
    int row = i >> 9, col = i & (HN - 1);
    float h = bf2f(hf[(size_t)row * HC + col]) + bf2f(hf[(size_t)row * HC + HN + col])
            + bf2f(hb[(size_t)row * HC + col]) + bf2f(hb[(size_t)row * HC + HN + col]);
    ushort_t hi = f2bf(h);
    hd[(size_t)row * HC + col] = hi;
    hd[(size_t)row * HC + HN + col] = f2bf(h - bf2f(hi));
}

// ===== Encoder step: both dirs, MT=128, 4 waves of 64x32 (NN=2). Grid (64,8). =====
// XCD = bx%8: dir = bx&4 (fwd XCD 0-3, bwd 4-7), rtile = (bx>>3)*4 + (bx&3).
// PD=3 single-barrier pipeline: stage(k+1) overwrites chunk k-2's buffer, whose
// reads completed before barrier(k-1) -> tail barrier dropped (race-audited).
// LDS 60 KB/block, 2 blocks/CU. 32 chunks (2-term split). Counted vmcnt(5).
__global__ __launch_bounds__(256, 2) void enc_step(
    const ushort_t* __restrict__ hf_in, ushort_t* __restrict__ hf_out,
    const ushort_t* __restrict__ BtF, const float* __restrict__ brF, const float* __restrict__ Pf,
    const ushort_t* __restrict__ hb_in, ushort_t* __restrict__ hb_out,
    const ushort_t* __restrict__ BtB, const float* __restrict__ brB, const float* __restrict__ Pb,
    const int* __restrict__ src, int t) {
    const int bx = blockIdx.x;
    const ushort_t* hin; ushort_t* hout; const ushort_t* Bt; const float* brec; const float* P; int rev;
    if ((bx & 4) == 0) { hin = hf_in; hout = hf_out; Bt = BtF; brec = brF; P = Pf; rev = 0; }
    else               { hin = hb_in; hout = hb_out; Bt = BtB; brec = brB; P = Pb; rev = 1; }
    const int bm = ((bx >> 3) * 4 + (bx & 3)) * 128;
    const int bj = blockIdx.y * 64;
    const int tid = threadIdx.x;
    const int lane = tid & 63;
    const int w = tid >> 6;
    const int wr = w >> 1, wc = w & 1;

    __shared__ __align__(16) short Asm[3][128 * 32];
    __shared__ __align__(16) short Bsm[3][192 * 32];

    f32x4 acc[3][4][2];
#pragma unroll
    for (int g = 0; g < 3; g++)
#pragma unroll
        for (int i = 0; i < 4; i++)
#pragma unroll
            for (int n = 0; n < 2; n++) acc[g][i][n] = (f32x4){0.f, 0.f, 0.f, 0.f};

    const int fl = lane & 15;
    const int fke = (((lane >> 4) ^ ((lane >> 1) & 3)) * 8);    // swizzled read slot
    const int lr = lane >> 2;
    const int lk = (((lane & 3) ^ ((lane >> 3) & 3)) * 8);      // swizzled global slot

    auto stage = [&](int buf, int kc) {
        const int agk = (kc < 16) ? (kc * 32) : (512 + (kc - 16) * 32);
        const int bkc = kc & 15;
#pragma unroll
        for (int s = 0; s < 2; ++s) {
            const int r0 = w * 32 + s * 16;
            gload16(hin + (size_t)(bm + r0 + lr) * HC + agk + lk, &Asm[buf][r0 * 32]);
        }
#pragma unroll
        for (int s = 0; s < 3; ++s) {
            const int r0 = w * 48 + s * 16;
            const int r = r0 + lr;
            const int gcol = ((r >> 6) << 9) + bj + (r & 63);
            gload16(Bt + ((size_t)bkc * GN + gcol) * 32 + lk, &Bsm[buf][r0 * 32]);
        }
    };

    auto compute = [&](int cur) {
        const short* Ab = Asm[cur];
        const short* Bb = Bsm[cur];
        bf16x8 af[4];
#pragma unroll
        for (int i = 0; i < 4; i++)
            af[i] = *(const bf16x8*)&Ab[(wr * 64 + i * 16 + fl) * 32 + fke];
#pragma unroll
        for (int g = 0; g < 3; g++) {
#pragma unroll
            for (int n = 0; n < 2; n++) {
                bf16x8 bfr = *(const bf16x8*)&Bb[(g * 64 + wc * 32 + n * 16 + fl) * 32 + fke];
#pragma unroll
                for (int i = 0; i < 4; i++)
                    acc[g][i][n] = __builtin_amdgcn_mfma_f32_16x16x32_bf16(af[i], bfr, acc[g][i][n], 0, 0, 0);
            }
        }
    };

    stage(0, 0);
    int cur = 0;
    for (int kc = 0; kc < 32; ++kc) {
        const int nxt = (cur == 2) ? 0 : cur + 1;
        if (kc < 31) { stage(nxt, kc + 1); waitcnt_vm<5>(); }
        else         { waitcnt_vm<0>(); }
        barrier_();
        compute(cur);
        cur = nxt;
    }

    const int fq = lane >> 4;
#pragma unroll
    for (int i = 0; i < 4; i++) {
#pragma unroll
        for (int q = 0; q < 4; q++) {
            const int row = bm + wr * 64 + i * 16 + fq * 4 + q;
            const int idx = src[row * SN + (rev ? (SN - 1 - t) : t)];
            const float* Pr = P + (size_t)idx * GN;
#pragma unroll
            for (int n = 0; n < 2; n++) {
                const int col = bj + wc * 32 + n * 16 + fl;
                float rz = acc[0][i][n][q] + brec[col];
                float rr = acc[1][i][n][q] + brec[HN + col];
                float rh = acc[2][i][n][q] + brec[2 * HN + col];
                float z = 1.f / (1.f + expf(-(Pr[col] + rz)));
                float r = 1.f / (1.f + expf(-(Pr[HN + col] + rr)));
                float hh = tanhf(Pr[2 * HN + col] + r * rh);
                float ho = bf2f(hin[(size_t)row * HC + col]) + bf2f(hin[(size_t)row * HC + HN + col]);
                float hnew = z * ho + (1.f - z) * hh;
                ushort_t hib = f2bf(hnew);
                hout[(size_t)row * HC + col] = hib;
                hout[(size_t)row * HC + HN + col] = f2bf(hnew - bf2f(hib));
            }
        }
    }
}

// ===== Fused decoder step t (32 chunks) + logits of step t-1 (48 chunks, 3-term). =====
// PD=3 single-barrier, LDS 48 KB, 3 blocks/CU.
__global__ __launch_bounds__(256, 3) void dec_fused(
    const ushort_t* __restrict__ hin, ushort_t* __restrict__ hout,
    const ushort_t* __restrict__ BtD, const float* __restrict__ brD, const float* __restrict__ Pd,
    const int* __restrict__ tgt, const ushort_t* __restrict__ Wot,
    const float* __restrict__ bo, float* __restrict__ out, int t) {
    const int bx = blockIdx.x;
    const int tid = threadIdx.x;
    const int lane = tid & 63;
    const int w = tid >> 6;
    const int fl = lane & 15;
    const int fke = (((lane >> 4) ^ ((lane >> 1) & 3)) * 8);
    const int lr = lane >> 2;
    const int lk = (((lane & 3) ^ ((lane >> 3) & 3)) * 8);
    const int fq = lane >> 4;

    __shared__ __align__(16) short SM[3][256 * 32];   // dec: A 64 rows + B 192 rows

    if (bx < 512) {
        const int bm = (bx & 63) * 64;
        const int bj = (bx >> 6) * 64;

        f32x4 acc[3][4];
#pragma unroll
        for (int g = 0; g < 3; g++)
#pragma unroll
            for (int i = 0; i < 4; i++) acc[g][i] = (f32x4){0.f, 0.f, 0.f, 0.f};

        auto stage = [&](int buf, int kc) {
            const int agk = (kc < 16) ? (kc * 32) : (512 + (kc - 16) * 32);
            const int bkc = kc & 15;
            const int r0a = w * 16;
            gload16(hin + (size_t)(bm + r0a + lr) * HC + agk + lk, &SM[buf][r0a * 32]);
#pragma unroll
            for (int s = 0; s < 3; ++s) {
                const int r0 = w * 48 + s * 16;
                const int r = r0 + lr;
                const int gcol = ((r >> 6) << 9) + bj + (r & 63);
                gload16(BtD + ((size_t)bkc * GN + gcol) * 32 + lk, &SM[buf][(64 + r0) * 32]);
            }
        };
        auto compute = [&](int cur) {
            const short* Ab = &SM[cur][0];
            const short* Bb = &SM[cur][64 * 32];
            bf16x8 af[4];
#pragma unroll
            for (int i = 0; i < 4; i++)
                af[i] = *(const bf16x8*)&Ab[(i * 16 + fl) * 32 + fke];
#pragma unroll
            for (int g = 0; g < 3; g++) {
                bf16x8 bfr = *(const bf16x8*)&Bb[(g * 64 + w * 16 + fl) * 32 + fke];
#pragma unroll
                for (int i = 0; i < 4; i++)
                    acc[g][i] = __builtin_amdgcn_mfma_f32_16x16x32_bf16(af[i], bfr, acc[g][i], 0, 0, 0);
            }
        };

        stage(0, 0);
        int cur = 0;
        for (int kc = 0; kc < 32; ++kc) {
            const int nxt = (cur == 2) ? 0 : cur + 1;
            if (kc < 31) { stage(nxt, kc + 1); waitcnt_vm<4>(); }
            else         { waitcnt_vm<0>(); }
            barrier_();
            compute(cur);
            cur = nxt;
        }

#pragma unroll
        for (int i = 0; i < 4; i++) {
#pragma unroll
            for (int q = 0; q < 4; q++) {
                const int row = bm + i * 16 + fq * 4 + q;
                const int idx = (t == 0) ? BOW_ : tgt[row * TN + (t - 1)];
                const float* Pr = Pd + (size_t)idx * GN;
                const int col = bj + w * 16 + fl;
                float rz = acc[0][i][q] + brD[col];
                float rr = acc[1][i][q] + brD[HN + col];
                float rh = acc[2][i][q] + brD[2 * HN + col];
                float z = 1.f / (1.f + expf(-(Pr[col] + rz)));
                float r = 1.f / (1.f + expf(-(Pr[HN + col] + rr)));
                float hh = tanhf(Pr[2 * HN + col] + r * rh);
                float ho = bf2f(hin[(size_t)row * HC + col]) + bf2f(hin[(size_t)row * HC + HN + col]);
                float hnew = z * ho + (1.f - z) * hh;
                ushort_t hib = f2bf(hnew);
                hout[(size_t)row * HC + col] = hib;
                hout[(size_t)row * HC + HN + col] = f2bf(hnew - bf2f(hib));
            }
        }
    } else {
        if (t == 0) return;
        const int l = bx - 512;
        const int bm = (l & 63) * 64;
        const int bn = (l >> 6) * 64;

        f32x4 acc[4];
#pragma unroll
        for (int i = 0; i < 4; i++) acc[i] = (f32x4){0.f, 0.f, 0.f, 0.f};

        auto stage = [&](int buf, int kc) {
            const int agk = (kc < 16) ? (kc * 32) : (kc < 32) ? (512 + (kc - 16) * 32) : ((kc - 32) * 32);
            const int bkc = (kc < 16) ? kc : (kc - 16);
            const int r0 = w * 16;
            gload16(hin + (size_t)(bm + r0 + lr) * HC + agk + lk, &SM[buf][r0 * 32]);
            gload16(Wot + ((size_t)bkc * VN + bn + r0 + lr) * 32 + lk, &SM[buf][(64 + r0) * 32]);
        };
        auto compute = [&](int cur) {
            const short* Ab = &SM[cur][0];
            const short* Bb = &SM[cur][64 * 32];
            bf16x8 bfr = *(const bf16x8*)&Bb[(w * 16 + fl) * 32 + fke];
#pragma unroll
            for (int i = 0; i < 4; i++) {
                bf16x8 af = *(const bf16x8*)&Ab[(i * 16 + fl) * 32 + fke];
                acc[i] = __builtin_amdgcn_mfma_f32_16x16x32_bf16(af, bfr, acc[i], 0, 0, 0);
            }
        };

        stage(0, 0);
        int cur = 0;
        for (int kc = 0; kc < 48; ++kc) {
            const int nxt = (cur == 2) ? 0 : cur + 1;
            if (kc < 47) { stage(nxt, kc + 1); waitcnt_vm<2>(); }
            else         { waitcnt_vm<0>(); }
            barrier_();
            compute(cur);
            cur = nxt;
        }

#pragma unroll
        for (int i = 0; i < 4; i++) {
#pragma unroll
            for (int q = 0; q < 4; q++) {
                const int row = bm + i * 16 + fq * 4 + q;
                const int col = bn + w * 16 + fl;
                out[(size_t)row * (TN * VN) + (t - 1) * VN + col] = acc[i][q] + bo[col];
            }
        }
    }
}

// standalone logits for the final decoder output (t = TN-1), 3-term split
__global__ __launch_bounds__(256) void logits_mfma(
    const ushort_t* __restrict__ hin, const ushort_t* __restrict__ Wot,
    const float* __restrict__ bo, float* __restrict__ out, int t) {
    const int bm = blockIdx.x * 64;
    const int bn = blockIdx.y * 64;
    const int tid = threadIdx.x;
    const int lane = tid & 63;
    const int w = tid >> 6;

    __shared__ __align__(16) short Asm[3][64 * 32];
    __shared__ __align__(16) short Bsm[3][64 * 32];

    f32x4 acc[4];
#pragma unroll
    for (int i = 0; i < 4; i++) acc[i] = (f32x4){0.f, 0.f, 0.f, 0.f};

    const int fl = lane & 15;
    const int fke = (((lane >> 4) ^ ((lane >> 1) & 3)) * 8);
    const int lr = lane >> 2;
    const int lk = (((lane & 3) ^ ((lane >> 3) & 3)) * 8);

    auto stage = [&](int buf, int kc) {
        const int agk = (kc < 16) ? (kc * 32) : (kc < 32) ? (512 + (kc - 16) * 32) : ((kc - 32) * 32);
        const int bkc = (kc < 16) ? kc : (kc - 16);
        const int r0 = w * 16;
        gload16(hin + (size_t)(bm + r0 + lr) * HC + agk + lk, &Asm[buf][r0 * 32]);
        gload16(Wot + ((size_t)bkc * VN + bn + r0 + lr) * 32 + lk, &Bsm[buf][r0 * 32]);
    };
    auto compute = [&](int cur) {
        const short* Ab = Asm[cur];
        const short* Bb = Bsm[cur];
        bf16x8 bfr = *(const bf16x8*)&Bb[(w * 16 + fl) * 32 + fke];
#pragma unroll
        for (int i = 0; i < 4; i++) {
            bf16x8 af = *(const bf16x8*)&Ab[(i * 16 + fl) * 32 + fke];
            acc[i] = __builtin_amdgcn_mfma_f32_16x16x32_bf16(af, bfr, acc[i], 0, 0, 0);
        }
    };

    stage(0, 0);
    int cur = 0;
    for (int kc = 0; kc < 48; ++kc) {
        const int nxt = (cur == 2) ? 0 : cur + 1;
        if (kc < 47) { stage(nxt, kc + 1); waitcnt_vm<2>(); }
        else         { waitcnt_vm<0>(); }
        barrier_();
        compute(cur);
        cur = nxt;
    }

    const int fq = lane >> 4;
#pragma unroll
    for (int i = 0; i < 4; i++) {
#pragma unroll
        for (int q = 0; q < 4; q++) {
            const int row = bm + i * 16 + fq * 4 + q;
            const int col = bn + w * 16 + fl;
            out[(size_t)row * (TN * VN) + t * VN + col] = acc[i][q] + bo[col];
        }
    }
}

extern "C" void kernel_launch(void* const* d_in, const int* in_sizes, int n_in,
                              void* d_out, int out_size, void* d_ws, size_t ws_size,
                              hipStream_t stream) {
    const int* source    = (const int*)d_in[0];
    const int* targets   = (const int*)d_in[1];
    const float* src_emb = (const float*)d_in[2];
    const float* tgt_emb = (const float*)d_in[3];
    const float* Wf = (const float*)d_in[4];
    const float* Uf = (const float*)d_in[5];
    const float* bf = (const float*)d_in[6];
    const float* Wb = (const float*)d_in[7];
    const float* Ub = (const float*)d_in[8];
    const float* bb = (const float*)d_in[9];
    const float* Wd = (const float*)d_in[10];
    const float* Ud = (const float*)d_in[11];
    const float* bd = (const float*)d_in[12];
    const float* Wo = (const float*)d_in[13];
    const float* bo = (const float*)d_in[14];
    float* out = (float*)d_out;

    char* ws = (char*)d_ws;
    ushort_t* BtF = (ushort_t*)(ws);                    // 16*1536*32*2 = 1572864 each
    ushort_t* BtB = (ushort_t*)(ws + 1572864);
    ushort_t* BtD = (ushort_t*)(ws + 2 * 1572864);
    ushort_t* Wot = (ushort_t*)(ws + 3 * 1572864);      // 32*256*32*2 = 524288
    float*    Pf  = (float*)   (ws + 3 * 1572864 + 524288);  // 3*256*1536*4 = 4718592
    float*    Pb  = Pf + VN * GN;
    float*    Pd  = Pb + VN * GN;
    char* hbase = ws + 3 * 1572864 + 524288 + 4718592;  // 4 x 4096*1024*2 = 4 x 8388608
    ushort_t* hf0 = (ushort_t*)(hbase);
    ushort_t* hf1 = (ushort_t*)(hbase + 8388608);
    ushort_t* hb0 = (ushort_t*)(hbase + 2 * 8388608);
    ushort_t* hb1 = (ushort_t*)(hbase + 3 * 8388608);

    // zero only the initial-state buffers (hf1/hb1 are fully written before read)
    zero_kernel<<<2048, 256, 0, stream>>>((float4*)hf0, 524288);
    zero_kernel<<<2048, 256, 0, stream>>>((float4*)hb0, 524288);
    precomp_P<<<dim3(4, 24, 3), 256, 0, stream>>>(src_emb, tgt_emb, Wf, bf, Wb, bb, Wd, bd, Pf, Pb, Pd);
    precomp_Bt2<<<48, 256, 0, stream>>>(Uf, Ub, Ud, BtF, BtB, BtD);
    precomp_Wot2<<<32, 256, 0, stream>>>(Wo, Wot);

    // encoder: grid (64,8): XCD 0-3 fwd / 4-7 bwd, 128-row tiles, 2 blocks/CU
    for (int t = 0; t < SN; t++) {
        const ushort_t* hfi = (t & 1) ? hf1 : hf0; ushort_t* hfo = (t & 1) ? hf0 : hf1;
        const ushort_t* hbi = (t & 1) ? hb1 : hb0; ushort_t* hbo = (t & 1) ? hb0 : hb1;
        enc_step<<<dim3(64, 8), 256, 0, stream>>>(
            hfi, hfo, BtF, bf + GN, Pf,
            hbi, hbo, BtB, bb + GN, Pb,
            source, t);
    }
    dec_init<<<(BN_ * HN + 255) / 256, 256, 0, stream>>>(hf0, hb0, hb1);

    // fused decoder step t + logits(t-1); ping-pong hb1 <-> hf1
    for (int t = 0; t < TN; t++) {
        const ushort_t* hdi = (t & 1) ? hf1 : hb1; ushort_t* hdo = (t & 1) ? hb1 : hf1;
        dec_fused<<<768, 256, 0, stream>>>(
            hdi, hdo, BtD, bd + GN, Pd, targets, Wot, bo, out, t);
    }
    // final logits for t = 23 output (hdo of t=23 is hb1 since 23 is odd)
    logits_mfma<<<dim3(64, 4), 256, 0, stream>>>(hb1, Wot, bo, out, TN - 1);
}